// Round 11
// baseline (571.629 us; speedup 1.0000x reference)
//
#include <hip/hip_runtime.h>
#include <hip/hip_bf16.h>

typedef __bf16 bf16_t;
typedef __bf16 bf16x2 __attribute__((ext_vector_type(2)));
typedef __bf16 bf16x8 __attribute__((ext_vector_type(8)));
typedef float f32x4 __attribute__((ext_vector_type(4)));

#define QSCALE 0.1803368801111396f   /* 0.125 * log2(e) */
#define MLOG2E 1.4426950408889634f
#define MCONST 12.0f                 /* static softmax max (log2 domain) */

__device__ __forceinline__ f32x4 mfma16(bf16x8 a, bf16x8 b, f32x4 c) {
  return __builtin_amdgcn_mfma_f32_16x16x32_bf16(a, b, c, 0, 0, 0);
}

#define GLDS16(gsrc, ldst)                                                     \
  __builtin_amdgcn_global_load_lds(                                            \
      (const __attribute__((address_space(1))) void*)(gsrc),                   \
      (__attribute__((address_space(3))) void*)(ldst), 16, 0, 0)

// pack two f32 -> one u32 of 2 bf16 (compiler emits v_cvt_pk_bf16_f32)
__device__ __forceinline__ unsigned pack2(float a, float b) {
  bf16x2 t = {(bf16_t)a, (bf16_t)b};
  return __builtin_bit_cast(unsigned, t);
}

// ---------------------------------------------------------------------------
// prep: rel f32(4095,64) -> bf16(4096,64); mbias = (1-mask)*-1e9*log2e
// ---------------------------------------------------------------------------
__global__ void prep_kernel(const float* __restrict__ rel,
                            const float* __restrict__ mask,
                            bf16_t* __restrict__ relb,
                            float* __restrict__ mbias) {
  int idx = blockIdx.x * 256 + threadIdx.x;
  if (idx < 4096 * 64) {
    int row = idx >> 6;
    int col = idx & 63;
    int sr = row > 4094 ? 4094 : row;
    relb[idx] = (bf16_t)rel[sr * 64 + col];
  } else {
    int j = idx - 4096 * 64;
    if (j < 4096) mbias[j] = (1.0f - mask[j]) * -1e9f * MLOG2E;
  }
}

// ---------------------------------------------------------------------------
// Fused projection GEMM: z=0 -> qb scaled by 0.125*log2e, (b,h,t,p) layout.
// z=1 -> kb (b,h,t,p).  z=2 -> vb TRANSPOSED (b,h,p,t).
// ---------------------------------------------------------------------------
__global__ __launch_bounds__(256) void proj_gemm_kernel(
    const float* __restrict__ Q, const float* __restrict__ K,
    const float* __restrict__ V, const float* __restrict__ WQ,
    const float* __restrict__ WK, const float* __restrict__ WV,
    bf16_t* __restrict__ qb, bf16_t* __restrict__ kb,
    bf16_t* __restrict__ vb) {
  const int z = blockIdx.z;
  const float* A = z == 0 ? Q : (z == 1 ? K : V);
  const float* W = z == 0 ? WQ : (z == 1 ? WK : WV);
  bf16_t* out = z == 0 ? qb : (z == 1 ? kb : vb);
  const float scale = z == 0 ? QSCALE : 1.0f;

  __shared__ bf16_t As[128][72];
  __shared__ bf16_t Bs[128][72];
  const int tid = threadIdx.x;
  const int lane = tid & 63;
  const int wid = tid >> 6;
  const int wm = wid >> 1, wn = wid & 1;
  const int row0 = blockIdx.x * 128;
  const int col0 = blockIdx.y * 128;
  const int lr = lane & 15;
  const int lk = (lane >> 4) * 8;

  f32x4 acc[4][4];
#pragma unroll
  for (int m = 0; m < 4; m++)
#pragma unroll
    for (int n = 0; n < 4; n++) acc[m][n] = {0.f, 0.f, 0.f, 0.f};

  for (int kt = 0; kt < 1024; kt += 64) {
#pragma unroll
    for (int i = 0; i < 4; i++) {
      int c = tid + i * 256;
      int row = c >> 3;
      int k8 = (c & 7) * 8;
      const float* src = A + (size_t)(row0 + row) * 1024 + kt + k8;
      float4 v0 = *(const float4*)(src);
      float4 v1 = *(const float4*)(src + 4);
      uint4 u = {pack2(v0.x, v0.y), pack2(v0.z, v0.w), pack2(v1.x, v1.y),
                 pack2(v1.z, v1.w)};
      *(uint4*)&As[row][k8] = u;
    }
#pragma unroll
    for (int i = 0; i < 4; i++) {
      int c = tid + i * 256;
      int col = c & 127;
      int k8 = (c >> 7) * 8;
      int gcol = col0 + col;
      int h = gcol >> 6, p = gcol & 63;
      const float* src = W + (size_t)h * 65536 + (size_t)(kt + k8) * 64 + p;
      float w0 = src[0], w1 = src[64], w2 = src[128], w3 = src[192];
      float w4 = src[256], w5 = src[320], w6 = src[384], w7 = src[448];
      uint4 u = {pack2(w0, w1), pack2(w2, w3), pack2(w4, w5), pack2(w6, w7)};
      *(uint4*)&Bs[col][k8] = u;
    }
    __syncthreads();
#pragma unroll
    for (int kk = 0; kk < 2; kk++) {
      bf16x8 af[4], bfr[4];
#pragma unroll
      for (int m = 0; m < 4; m++)
        af[m] = *(const bf16x8*)&As[wm * 64 + m * 16 + lr][kk * 32 + lk];
#pragma unroll
      for (int n = 0; n < 4; n++)
        bfr[n] = *(const bf16x8*)&Bs[wn * 64 + n * 16 + lr][kk * 32 + lk];
#pragma unroll
      for (int m = 0; m < 4; m++)
#pragma unroll
        for (int n = 0; n < 4; n++)
          acc[m][n] = mfma16(af[m], bfr[n], acc[m][n]);
    }
    __syncthreads();
  }
  const int rb = (lane >> 4) * 4;
#pragma unroll
  for (int m = 0; m < 4; m++) {
#pragma unroll
    for (int n = 0; n < 4; n++) {
      int col = col0 + wn * 64 + n * 16 + lr;
      int h = col >> 6, p = col & 63;
      int row_base = row0 + wm * 64 + m * 16 + rb;
      int b = row_base >> 11, t0 = row_base & 2047;
      if (z == 2) {
        uint2 u = {pack2(acc[m][n][0], acc[m][n][1]),
                   pack2(acc[m][n][2], acc[m][n][3])};
        *(uint2*)&out[(((size_t)(b * 16 + h) * 64 + p) * 2048) + t0] = u;
      } else {
#pragma unroll
        for (int r = 0; r < 4; r++) {
          out[(((size_t)(b * 16 + h) * 2048 + t0 + r) * 64) + p] =
              (bf16_t)(acc[m][n][r] * scale);
        }
      }
    }
  }
}

// ---------------------------------------------------------------------------
// Dense output GEMM: out = (octx * 1/l)(->bf16) @ W(f32) + bias.
// The 1/l normalization and f32->bf16 convert are folded into A-staging.
// ---------------------------------------------------------------------------
__global__ __launch_bounds__(256) void dense_gemm_kernel(
    const float* __restrict__ octx, const float* __restrict__ lbuf,
    const float* __restrict__ W, const float* __restrict__ bias,
    float* __restrict__ out) {
  __shared__ bf16_t As[128][72];
  __shared__ bf16_t Bs[128][72];
  const int tid = threadIdx.x;
  const int lane = tid & 63;
  const int wid = tid >> 6;
  const int wm = wid >> 1, wn = wid & 1;
  const int row0 = blockIdx.x * 128;
  const int col0 = blockIdx.y * 128;
  const int lr = lane & 15;
  const int lk = (lane >> 4) * 8;

  f32x4 acc[4][4];
#pragma unroll
  for (int m = 0; m < 4; m++)
#pragma unroll
    for (int n = 0; n < 4; n++) acc[m][n] = {0.f, 0.f, 0.f, 0.f};

  for (int kt = 0; kt < 1024; kt += 64) {
#pragma unroll
    for (int i = 0; i < 4; i++) {
      int c = tid + i * 256;
      int row = row0 + (c >> 3);
      int k8 = (c & 7) * 8;
      int gk = kt + k8;
      const float* src = octx + (size_t)row * 1024 + gk;
      float invl =
          1.0f / lbuf[(size_t)(((row >> 11) << 4) + (gk >> 6)) * 2048 +
                      (row & 2047)];
      float4 v0 = *(const float4*)(src);
      float4 v1 = *(const float4*)(src + 4);
      uint4 u = {pack2(v0.x * invl, v0.y * invl), pack2(v0.z * invl, v0.w * invl),
                 pack2(v1.x * invl, v1.y * invl), pack2(v1.z * invl, v1.w * invl)};
      *(uint4*)&As[c >> 3][k8] = u;
    }
#pragma unroll
    for (int i = 0; i < 4; i++) {
      int c = tid + i * 256;
      int col = c & 127;
      int k8 = (c >> 7) * 8;
      const float* src = W + (size_t)(kt + k8) * 1024 + col0 + col;
      float w0 = src[0], w1 = src[1024], w2 = src[2048], w3 = src[3072];
      float w4 = src[4096], w5 = src[5120], w6 = src[6144], w7 = src[7168];
      uint4 u = {pack2(w0, w1), pack2(w2, w3), pack2(w4, w5), pack2(w6, w7)};
      *(uint4*)&Bs[col][k8] = u;
    }
    __syncthreads();
#pragma unroll
    for (int kk = 0; kk < 2; kk++) {
      bf16x8 af[4], bfr[4];
#pragma unroll
      for (int m = 0; m < 4; m++)
        af[m] = *(const bf16x8*)&As[wm * 64 + m * 16 + lr][kk * 32 + lk];
#pragma unroll
      for (int n = 0; n < 4; n++)
        bfr[n] = *(const bf16x8*)&Bs[wn * 64 + n * 16 + lr][kk * 32 + lk];
#pragma unroll
      for (int m = 0; m < 4; m++)
#pragma unroll
        for (int n = 0; n < 4; n++)
          acc[m][n] = mfma16(af[m], bfr[n], acc[m][n]);
    }
    __syncthreads();
  }
  const int rb = (lane >> 4) * 4;
#pragma unroll
  for (int m = 0; m < 4; m++) {
#pragma unroll
    for (int n = 0; n < 4; n++) {
      int col = col0 + wn * 64 + n * 16 + lr;
      float bv = bias[col];
#pragma unroll
      for (int r = 0; r < 4; r++) {
        int row = row0 + wm * 64 + m * 16 + rb + r;
        out[(size_t)row * 1024 + col] = acc[m][n][r] + bv;
      }
    }
  }
}

// ---------------------------------------------------------------------------
// Flash attention, swapped-operand, QBLK=128, jt-range split 3 ways.
// Static-max softmax makes split partials directly summable: blocks
// atomicAdd o into octx (f32) and l into lbuf.  R fragments load directly
// global->VGPR (relb is 512 KB, L2-hot); K/V double-buffered in LDS.
// LDS 43 KB -> 3 blocks/CU; grid 1536 = 2 clean rounds.
// ---------------------------------------------------------------------------
__global__ __launch_bounds__(256, 3) void attn_kernel(
    const bf16_t* __restrict__ qg, const bf16_t* __restrict__ kg,
    const bf16_t* __restrict__ vt, const bf16_t* __restrict__ relb,
    const float* __restrict__ mbias, float* __restrict__ octx,
    float* __restrict__ lbuf) {
  __shared__ bf16_t Kb[2][64 * 64];  // 16 KB
  __shared__ bf16_t Vb[2][64 * 64];  // 16 KB
  __shared__ unsigned SC[4][688];    // 11 KB per-wave EL/PL scratch

  const int tid = threadIdx.x;
  const int lane = tid & 63;
  const int w = tid >> 6;

  const int id = blockIdx.x;
  const int sidx = id >> 9;        // jt-split index 0..2
  const int rid = id & 511;
  // XCD-bijective remap (512 = 8 x 64)
  const int id2 = (rid & 7) * 64 + (rid >> 3);
  const int it = id2 & 15;
  const int bh = id2 >> 4;
  const int h = bh & 15;
  const int b = bh >> 4;
  const int i0 = it * 128;
  const int jt0 = sidx * 11;
  const int jt1 = sidx == 2 ? 32 : jt0 + 11;

  const size_t base = ((size_t)bh) * 2048 * 64;
  const int lr = lane & 15;
  const int g = lane >> 4;
  const int lk = g * 8;
  const int srow = lane >> 3;  // staging row-within-chunk
  const int t16 = lane & 7;    // staging 16B slot
  const int swz = (lr & 7) << 3;

  const bf16_t* kgb = kg + base;
  const bf16_t* vgb = vt + base;
  // R fragment base for this lane (col = kk*32 + lk added per use)
  const bf16_t* rgb = relb + (size_t)(1920 - i0) * 64 + lk;

  // Q fragments: two groups (queries i0 + w*32 + gq*16 + lr)
  bf16x8 aq[2][2];
#pragma unroll
  for (int gq = 0; gq < 2; gq++) {
    const bf16_t* src =
        qg + base + (size_t)(i0 + w * 32 + gq * 16 + lr) * 64 + lk;
    aq[gq][0] = *(const bf16x8*)(src);
    aq[gq][1] = *(const bf16x8*)(src + 32);
  }

  float l0 = 0.f, l1 = 0.f;  // in-lane partial denominators
  f32x4 o0[4], o1[4];
#pragma unroll
  for (int n = 0; n < 4; n++) {
    o0[n] = {0.f, 0.f, 0.f, 0.f};
    o1[n] = {0.f, 0.f, 0.f, 0.f};
  }

  const float* mb_base = mbias + (size_t)b * 2048;
  unsigned* scw = SC[w];
  int sh[4];
#pragma unroll
  for (int r = 0; r < 4; r++) sh[r] = ((r + lr + 1) & 1) << 4;

  // ---- prologue: K[jt0]->Kb[0], V[jt0]->Vb[0]
#pragma unroll
  for (int i = 0; i < 2; i++) {
    int chunk = i * 4 + w;
    int row = chunk * 8 + srow;
    GLDS16(kgb + (size_t)(jt0 * 64 + row) * 64 + ((t16 ^ (row & 7)) * 8),
           Kb[0] + chunk * 512 + lane * 8);
  }
#pragma unroll
  for (int i = 0; i < 2; i++) {
    int chunk = i * 4 + w;
    int p = chunk * 8 + srow;
    GLDS16(vgb + jt0 * 64 + (size_t)p * 2048 + ((t16 ^ (p & 7)) * 8),
           Vb[0] + chunk * 512 + lane * 8);
  }
  __syncthreads();

  int lt = 0;
  for (int jt = jt0; jt < jt1; ++jt, ++lt) {
    const int j0 = jt * 64;
    const int cur = lt & 1;

    // ---- mask-bias loads first
    f32x4 mbv[4];
#pragma unroll
    for (int n = 0; n < 4; n++)
      mbv[n] = *(const f32x4*)&mb_base[j0 + n * 16 + g * 4];

    // ---- R fragments kk=0 half: direct global->VGPR (L2-hot)
    const bf16_t* rb0 = rgb + (size_t)j0 * 64;
    bf16x8 ar0[6];
#pragma unroll
    for (int fi = 0; fi < 6; fi++) {
      int f = 6 - 2 * w + fi;
      ar0[fi] = *(const bf16x8*)(rb0 + (size_t)(f * 16 + lr) * 64);
    }

    // ---- stage next K/V tiles (drain at this phase's single barrier)
    if (jt + 1 < jt1) {
#pragma unroll
      for (int i = 0; i < 2; i++) {
        int chunk = i * 4 + w;
        int p = chunk * 8 + srow;
        GLDS16(vgb + (j0 + 64) + (size_t)p * 2048 + ((t16 ^ (p & 7)) * 8),
               Vb[cur ^ 1] + chunk * 512 + lane * 8);
      }
      const bf16_t* kn = kgb + (size_t)(j0 + 64) * 64;
#pragma unroll
      for (int i = 0; i < 2; i++) {
        int chunk = i * 4 + w;
        int row = chunk * 8 + srow;
        GLDS16(kn + row * 64 + ((t16 ^ (row & 7)) * 8),
               Kb[cur ^ 1] + chunk * 512 + lane * 8);
      }
    }

    // ---- QK + rel band MFMAs
    f32x4 sacc0[4], sacc1[4], er0[5], er1[5];
#pragma unroll
    for (int n = 0; n < 4; n++) {
      sacc0[n] = {0.f, 0.f, 0.f, 0.f};
      sacc1[n] = {0.f, 0.f, 0.f, 0.f};
    }
#pragma unroll
    for (int n = 0; n < 5; n++) {
      er0[n] = {0.f, 0.f, 0.f, 0.f};
      er1[n] = {0.f, 0.f, 0.f, 0.f};
    }
    const bf16_t* kcur = Kb[cur];
    __builtin_amdgcn_s_setprio(1);
    {  // kk = 0 QK
      int cbs = lk ^ swz;
#pragma unroll
      for (int n = 0; n < 4; n++) {
        bf16x8 ak = *(const bf16x8*)&kcur[(n * 16 + lr) * 64 + cbs];
        sacc0[n] = mfma16(ak, aq[0][0], sacc0[n]);
        sacc1[n] = mfma16(ak, aq[1][0], sacc1[n]);
      }
    }
    // R fragments kk=1 half (issued here; cover = er kk0 + QK kk1 MFMAs)
    bf16x8 ar1[6];
#pragma unroll
    for (int fi = 0; fi < 6; fi++) {
      int f = 6 - 2 * w + fi;
      ar1[fi] = *(const bf16x8*)(rb0 + 32 + (size_t)(f * 16 + lr) * 64);
    }
    // er kk0
#pragma unroll
    for (int fi = 0; fi < 6; fi++) {
      if (fi >= 1) er0[fi - 1] = mfma16(ar0[fi], aq[0][0], er0[fi - 1]);
      if (fi <= 4) er1[fi] = mfma16(ar0[fi], aq[1][0], er1[fi]);
    }
    {  // kk = 1 QK
      int cbs = (32 + lk) ^ swz;
#pragma unroll
      for (int n = 0; n < 4; n++) {
        bf16x8 ak = *(const bf16x8*)&kcur[(n * 16 + lr) * 64 + cbs];
        sacc0[n] = mfma16(ak, aq[0][1], sacc0[n]);
        sacc1[n] = mfma16(ak, aq[1][1], sacc1[n]);
      }
    }
    // er kk1
#pragma unroll
    for (int fi = 0; fi < 6; fi++) {
      if (fi >= 1) er0[fi - 1] = mfma16(ar1[fi], aq[0][1], er0[fi - 1]);
      if (fi <= 4) er1[fi] = mfma16(ar1[fi], aq[1][1], er1[fi]);
    }
    __builtin_amdgcn_s_setprio(0);

    // ---- softmax both groups through shared per-wave scratch (static max)
    bf16x8 bp0[2], bp1[2];
#pragma unroll
    for (int gq = 0; gq < 2; gq++) {
      f32x4* sacc = gq ? sacc1 : sacc0;
      f32x4* er = gq ? er1 : er0;
#pragma unroll
      for (int n2 = 0; n2 < 5; n2++) {
        uint2 u = {pack2(er[n2][0], er[n2][1]), pack2(er[n2][2], er[n2][3])};
        *(uint2*)&scw[lr * 42 + n2 * 8 + g * 2] = u;
      }
      float ps = 0.f;
      float e[4][4];
#pragma unroll
      for (int n = 0; n < 4; n++) {
#pragma unroll
        for (int r = 0; r < 4; r++) {
          int key = n * 16 + g * 4 + r;
          int idx = key - lr + 15;  // in [0,78]
          unsigned d = scw[lr * 42 + (idx >> 1)];
          float bias = __builtin_bit_cast(float, (d >> sh[r]) << 16);
          float s = sacc[n][r] + bias + mbv[n][r];
          e[n][r] = exp2f(s - MCONST);
          ps += e[n][r];
        }
      }
      if (gq) l1 += ps; else l0 += ps;
#pragma unroll
      for (int n = 0; n < 4; n++) {
        uint2 u = {pack2(e[n][0], e[n][1]), pack2(e[n][2], e[n][3])};
        *(uint2*)&scw[lr * 36 + n * 8 + g * 2] = u;
      }
      uint4 t0 = *(const uint4*)&scw[lr * 36 + g * 4];
      uint4 t1 = *(const uint4*)&scw[lr * 36 + 16 + g * 4];
      if (gq) {
        bp1[0] = __builtin_bit_cast(bf16x8, t0);
        bp1[1] = __builtin_bit_cast(bf16x8, t1);
      } else {
        bp0[0] = __builtin_bit_cast(bf16x8, t0);
        bp0[1] = __builtin_bit_cast(bf16x8, t1);
      }
    }

    // ---- ctx^T += V^T P
    const bf16_t* vcur = Vb[cur];
    __builtin_amdgcn_s_setprio(1);
#pragma unroll
    for (int kk = 0; kk < 2; kk++) {
      int cbs = (kk * 32 + lk) ^ swz;
#pragma unroll
      for (int n = 0; n < 4; n++) {
        bf16x8 av = *(const bf16x8*)&vcur[(n * 16 + lr) * 64 + cbs];
        o0[n] = mfma16(av, bp0[kk], o0[n]);
        o1[n] = mfma16(av, bp1[kk], o1[n]);
      }
    }
    __builtin_amdgcn_s_setprio(0);

    __syncthreads();  // single barrier: drains staging, orders buffer reuse
  }

  // ---- cross-group l reduction, then atomics into lbuf / octx
  l0 += __shfl_xor(l0, 16, 64);
  l0 += __shfl_xor(l0, 32, 64);
  l1 += __shfl_xor(l1, 16, 64);
  l1 += __shfl_xor(l1, 32, 64);

#pragma unroll
  for (int gq = 0; gq < 2; gq++) {
    f32x4* o = gq ? o1 : o0;
    int q = i0 + w * 32 + gq * 16 + lr;
    if (g == 0) atomicAdd(&lbuf[(size_t)bh * 2048 + q], gq ? l1 : l0);
    size_t bt = (size_t)b * 2048 + q;
    float* dst = octx + bt * 1024 + h * 64 + g * 4;
#pragma unroll
    for (int n = 0; n < 4; n++) {
#pragma unroll
      for (int r = 0; r < 4; r++) atomicAdd(dst + n * 16 + r, o[n][r]);
    }
  }
}

// ---------------------------------------------------------------------------
extern "C" void kernel_launch(void* const* d_in, const int* in_sizes, int n_in,
                              void* d_out, int out_size, void* d_ws,
                              size_t ws_size, hipStream_t stream) {
  (void)in_sizes; (void)n_in; (void)out_size; (void)ws_size;
  const float* Q    = (const float*)d_in[0];
  const float* K    = (const float*)d_in[1];
  const float* V    = (const float*)d_in[2];
  const float* mask = (const float*)d_in[3];
  const float* WQ   = (const float*)d_in[4];
  const float* WK   = (const float*)d_in[5];
  const float* WV   = (const float*)d_in[6];
  const float* rel  = (const float*)d_in[7];
  const float* dW   = (const float*)d_in[8];
  const float* db   = (const float*)d_in[9];
  float* out = (float*)d_out;

  const size_t NQKV = (size_t)2 * 16 * 2048 * 64;  // 4,194,304
  bf16_t* qb   = (bf16_t*)d_ws;
  bf16_t* kb   = qb + NQKV;
  bf16_t* vb   = kb + NQKV;                    // V^T (b,h,p,t)
  bf16_t* relb = vb + NQKV;                    // 4096*64 bf16
  float*  mbias = (float*)(relb + 4096 * 64);  // 4096 f32
  float*  octx = mbias + 4096;                 // 4096*1024 f32
  float*  lbuf = octx + (size_t)4096 * 1024;   // 2*16*2048 f32

  dim3 blk(256);
  prep_kernel<<<dim3((4096 * 64 + 4096) / 256), blk, 0, stream>>>(rel, mask,
                                                                  relb, mbias);
  proj_gemm_kernel<<<dim3(32, 8, 3), blk, 0, stream>>>(Q, K, V, WQ, WK, WV, qb,
                                                       kb, vb);
  hipMemsetAsync(octx, 0, ((size_t)4096 * 1024 + 2 * 16 * 2048) * sizeof(float),
                 stream);
  attn_kernel<<<dim3(1536), blk, 0, stream>>>(qb, kb, vb, relb, mbias, octx,
                                              lbuf);
  dense_gemm_kernel<<<dim3(32, 8), blk, 0, stream>>>(octx, lbuf, dW, db, out);
}

// Round 12
// 482.028 us; speedup vs baseline: 1.1859x; 1.1859x over previous
//
#include <hip/hip_runtime.h>
#include <hip/hip_bf16.h>

typedef __bf16 bf16_t;
typedef __bf16 bf16x2 __attribute__((ext_vector_type(2)));
typedef __bf16 bf16x8 __attribute__((ext_vector_type(8)));
typedef float f32x4 __attribute__((ext_vector_type(4)));

#define QSCALE 0.1803368801111396f   /* 0.125 * log2(e) */
#define MLOG2E 1.4426950408889634f
#define MCONST 12.0f                 /* static softmax max (log2 domain) */

__device__ __forceinline__ f32x4 mfma16(bf16x8 a, bf16x8 b, f32x4 c) {
  return __builtin_amdgcn_mfma_f32_16x16x32_bf16(a, b, c, 0, 0, 0);
}

#define GLDS16(gsrc, ldst)                                                     \
  __builtin_amdgcn_global_load_lds(                                            \
      (const __attribute__((address_space(1))) void*)(gsrc),                   \
      (__attribute__((address_space(3))) void*)(ldst), 16, 0, 0)

// pack two f32 -> one u32 of 2 bf16 (compiler emits v_cvt_pk_bf16_f32)
__device__ __forceinline__ unsigned pack2(float a, float b) {
  bf16x2 t = {(bf16_t)a, (bf16_t)b};
  return __builtin_bit_cast(unsigned, t);
}

// ---------------------------------------------------------------------------
// prep: rel f32(4095,64) -> bf16(4096,64); mbias = (1-mask)*-1e9*log2e
// ---------------------------------------------------------------------------
__global__ void prep_kernel(const float* __restrict__ rel,
                            const float* __restrict__ mask,
                            bf16_t* __restrict__ relb,
                            float* __restrict__ mbias) {
  int idx = blockIdx.x * 256 + threadIdx.x;
  if (idx < 4096 * 64) {
    int row = idx >> 6;
    int col = idx & 63;
    int sr = row > 4094 ? 4094 : row;
    relb[idx] = (bf16_t)rel[sr * 64 + col];
  } else {
    int j = idx - 4096 * 64;
    if (j < 4096) mbias[j] = (1.0f - mask[j]) * -1e9f * MLOG2E;
  }
}

// ---------------------------------------------------------------------------
// Fused projection GEMM: z=0 -> qb scaled by 0.125*log2e, (b,h,t,p) layout.
// z=1 -> kb (b,h,t,p).  z=2 -> vb TRANSPOSED (b,h,p,t).
// ---------------------------------------------------------------------------
__global__ __launch_bounds__(256) void proj_gemm_kernel(
    const float* __restrict__ Q, const float* __restrict__ K,
    const float* __restrict__ V, const float* __restrict__ WQ,
    const float* __restrict__ WK, const float* __restrict__ WV,
    bf16_t* __restrict__ qb, bf16_t* __restrict__ kb,
    bf16_t* __restrict__ vb) {
  const int z = blockIdx.z;
  const float* A = z == 0 ? Q : (z == 1 ? K : V);
  const float* W = z == 0 ? WQ : (z == 1 ? WK : WV);
  bf16_t* out = z == 0 ? qb : (z == 1 ? kb : vb);
  const float scale = z == 0 ? QSCALE : 1.0f;

  __shared__ bf16_t As[128][72];
  __shared__ bf16_t Bs[128][72];
  const int tid = threadIdx.x;
  const int lane = tid & 63;
  const int wid = tid >> 6;
  const int wm = wid >> 1, wn = wid & 1;
  const int row0 = blockIdx.x * 128;
  const int col0 = blockIdx.y * 128;
  const int lr = lane & 15;
  const int lk = (lane >> 4) * 8;

  f32x4 acc[4][4];
#pragma unroll
  for (int m = 0; m < 4; m++)
#pragma unroll
    for (int n = 0; n < 4; n++) acc[m][n] = {0.f, 0.f, 0.f, 0.f};

  for (int kt = 0; kt < 1024; kt += 64) {
#pragma unroll
    for (int i = 0; i < 4; i++) {
      int c = tid + i * 256;
      int row = c >> 3;
      int k8 = (c & 7) * 8;
      const float* src = A + (size_t)(row0 + row) * 1024 + kt + k8;
      float4 v0 = *(const float4*)(src);
      float4 v1 = *(const float4*)(src + 4);
      uint4 u = {pack2(v0.x, v0.y), pack2(v0.z, v0.w), pack2(v1.x, v1.y),
                 pack2(v1.z, v1.w)};
      *(uint4*)&As[row][k8] = u;
    }
#pragma unroll
    for (int i = 0; i < 4; i++) {
      int c = tid + i * 256;
      int col = c & 127;
      int k8 = (c >> 7) * 8;
      int gcol = col0 + col;
      int h = gcol >> 6, p = gcol & 63;
      const float* src = W + (size_t)h * 65536 + (size_t)(kt + k8) * 64 + p;
      float w0 = src[0], w1 = src[64], w2 = src[128], w3 = src[192];
      float w4 = src[256], w5 = src[320], w6 = src[384], w7 = src[448];
      uint4 u = {pack2(w0, w1), pack2(w2, w3), pack2(w4, w5), pack2(w6, w7)};
      *(uint4*)&Bs[col][k8] = u;
    }
    __syncthreads();
#pragma unroll
    for (int kk = 0; kk < 2; kk++) {
      bf16x8 af[4], bfr[4];
#pragma unroll
      for (int m = 0; m < 4; m++)
        af[m] = *(const bf16x8*)&As[wm * 64 + m * 16 + lr][kk * 32 + lk];
#pragma unroll
      for (int n = 0; n < 4; n++)
        bfr[n] = *(const bf16x8*)&Bs[wn * 64 + n * 16 + lr][kk * 32 + lk];
#pragma unroll
      for (int m = 0; m < 4; m++)
#pragma unroll
        for (int n = 0; n < 4; n++)
          acc[m][n] = mfma16(af[m], bfr[n], acc[m][n]);
    }
    __syncthreads();
  }
  const int rb = (lane >> 4) * 4;
#pragma unroll
  for (int m = 0; m < 4; m++) {
#pragma unroll
    for (int n = 0; n < 4; n++) {
      int col = col0 + wn * 64 + n * 16 + lr;
      int h = col >> 6, p = col & 63;
      int row_base = row0 + wm * 64 + m * 16 + rb;
      int b = row_base >> 11, t0 = row_base & 2047;
      if (z == 2) {
        uint2 u = {pack2(acc[m][n][0], acc[m][n][1]),
                   pack2(acc[m][n][2], acc[m][n][3])};
        *(uint2*)&out[(((size_t)(b * 16 + h) * 64 + p) * 2048) + t0] = u;
      } else {
#pragma unroll
        for (int r = 0; r < 4; r++) {
          out[(((size_t)(b * 16 + h) * 2048 + t0 + r) * 64) + p] =
              (bf16_t)(acc[m][n][r] * scale);
        }
      }
    }
  }
}

// ---------------------------------------------------------------------------
// Dense output GEMM: out = (sum_s octx_s * 1/sum_s l_s)(->bf16) @ W + bias.
// Slice-sum, normalization and bf16 convert folded into A-staging.
// ---------------------------------------------------------------------------
__global__ __launch_bounds__(256) void dense_gemm_kernel(
    const float* __restrict__ octx, const float* __restrict__ lbuf,
    const float* __restrict__ W, const float* __restrict__ bias,
    float* __restrict__ out) {
  __shared__ bf16_t As[128][72];
  __shared__ bf16_t Bs[128][72];
  const int tid = threadIdx.x;
  const int lane = tid & 63;
  const int wid = tid >> 6;
  const int wm = wid >> 1, wn = wid & 1;
  const int row0 = blockIdx.x * 128;
  const int col0 = blockIdx.y * 128;
  const int lr = lane & 15;
  const int lk = (lane >> 4) * 8;
  const size_t OSL = (size_t)4096 * 1024;  // octx slice stride
  const int LSL = 2 * 16 * 2048;           // lbuf slice stride

  f32x4 acc[4][4];
#pragma unroll
  for (int m = 0; m < 4; m++)
#pragma unroll
    for (int n = 0; n < 4; n++) acc[m][n] = {0.f, 0.f, 0.f, 0.f};

  for (int kt = 0; kt < 1024; kt += 64) {
#pragma unroll
    for (int i = 0; i < 4; i++) {
      int c = tid + i * 256;
      int row = row0 + (c >> 3);
      int k8 = (c & 7) * 8;
      int gk = kt + k8;
      int lidx = (((row >> 11) << 4) + (gk >> 6)) * 2048 + (row & 2047);
      float invl = 1.0f / (lbuf[lidx] + lbuf[lidx + LSL] + lbuf[lidx + 2 * LSL]);
      const float* s0 = octx + (size_t)row * 1024 + gk;
      float4 a0 = *(const float4*)(s0);
      float4 a1 = *(const float4*)(s0 + 4);
      float4 b0 = *(const float4*)(s0 + OSL);
      float4 b1 = *(const float4*)(s0 + OSL + 4);
      float4 c0 = *(const float4*)(s0 + 2 * OSL);
      float4 c1 = *(const float4*)(s0 + 2 * OSL + 4);
      float v0 = (a0.x + b0.x + c0.x) * invl, v1 = (a0.y + b0.y + c0.y) * invl;
      float v2 = (a0.z + b0.z + c0.z) * invl, v3 = (a0.w + b0.w + c0.w) * invl;
      float v4 = (a1.x + b1.x + c1.x) * invl, v5 = (a1.y + b1.y + c1.y) * invl;
      float v6 = (a1.z + b1.z + c1.z) * invl, v7 = (a1.w + b1.w + c1.w) * invl;
      uint4 u = {pack2(v0, v1), pack2(v2, v3), pack2(v4, v5), pack2(v6, v7)};
      *(uint4*)&As[c >> 3][k8] = u;
    }
#pragma unroll
    for (int i = 0; i < 4; i++) {
      int c = tid + i * 256;
      int col = c & 127;
      int k8 = (c >> 7) * 8;
      const float* src = W + (size_t)(kt + k8) * 1024 + col0 + col;
      float w0 = src[0], w1 = src[1024], w2 = src[2048], w3 = src[3072];
      float w4 = src[4096], w5 = src[5120], w6 = src[6144], w7 = src[7168];
      uint4 u = {pack2(w0, w1), pack2(w2, w3), pack2(w4, w5), pack2(w6, w7)};
      *(uint4*)&Bs[col][k8] = u;
    }
    __syncthreads();
#pragma unroll
    for (int kk = 0; kk < 2; kk++) {
      bf16x8 af[4], bfr[4];
#pragma unroll
      for (int m = 0; m < 4; m++)
        af[m] = *(const bf16x8*)&As[wm * 64 + m * 16 + lr][kk * 32 + lk];
#pragma unroll
      for (int n = 0; n < 4; n++)
        bfr[n] = *(const bf16x8*)&Bs[wn * 64 + n * 16 + lr][kk * 32 + lk];
#pragma unroll
      for (int m = 0; m < 4; m++)
#pragma unroll
        for (int n = 0; n < 4; n++)
          acc[m][n] = mfma16(af[m], bfr[n], acc[m][n]);
    }
    __syncthreads();
  }
  const int rb = (lane >> 4) * 4;
#pragma unroll
  for (int m = 0; m < 4; m++) {
#pragma unroll
    for (int n = 0; n < 4; n++) {
      int col = col0 + wn * 64 + n * 16 + lr;
      float bv = bias[col];
#pragma unroll
      for (int r = 0; r < 4; r++) {
        int row = row0 + wm * 64 + m * 16 + rb + r;
        out[(size_t)row * 1024 + col] = acc[m][n][r] + bv;
      }
    }
  }
}

// ---------------------------------------------------------------------------
// Flash attention, swapped-operand, QBLK=128, jt-range split 3 ways.
// Static-max softmax => split partials directly summable.  Each split writes
// its own f32 octx/lbuf slice (coalesced stores, NO atomics); dense combines.
// R fragments direct global->VGPR (L2-hot); K/V double-buffered in LDS.
// LDS 43 KB -> 3 blocks/CU; grid 1536 = 2 clean rounds.
// ---------------------------------------------------------------------------
__global__ __launch_bounds__(256, 3) void attn_kernel(
    const bf16_t* __restrict__ qg, const bf16_t* __restrict__ kg,
    const bf16_t* __restrict__ vt, const bf16_t* __restrict__ relb,
    const float* __restrict__ mbias, float* __restrict__ octx,
    float* __restrict__ lbuf) {
  __shared__ bf16_t Kb[2][64 * 64];  // 16 KB
  __shared__ bf16_t Vb[2][64 * 64];  // 16 KB
  __shared__ unsigned SC[4][688];    // 11 KB per-wave EL/PL scratch

  const int tid = threadIdx.x;
  const int lane = tid & 63;
  const int w = tid >> 6;

  const int id = blockIdx.x;
  const int sidx = id >> 9;        // jt-split index 0..2
  const int rid = id & 511;
  // XCD-bijective remap (512 = 8 x 64)
  const int id2 = (rid & 7) * 64 + (rid >> 3);
  const int it = id2 & 15;
  const int bh = id2 >> 4;
  const int h = bh & 15;
  const int b = bh >> 4;
  const int i0 = it * 128;
  const int jt0 = sidx * 11;
  const int jt1 = sidx == 2 ? 32 : jt0 + 11;

  const size_t base = ((size_t)bh) * 2048 * 64;
  const int lr = lane & 15;
  const int g = lane >> 4;
  const int lk = g * 8;
  const int srow = lane >> 3;  // staging row-within-chunk
  const int t16 = lane & 7;    // staging 16B slot
  const int swz = (lr & 7) << 3;

  const bf16_t* kgb = kg + base;
  const bf16_t* vgb = vt + base;
  const bf16_t* rgb = relb + (size_t)(1920 - i0) * 64 + lk;

  bf16x8 aq[2][2];
#pragma unroll
  for (int gq = 0; gq < 2; gq++) {
    const bf16_t* src =
        qg + base + (size_t)(i0 + w * 32 + gq * 16 + lr) * 64 + lk;
    aq[gq][0] = *(const bf16x8*)(src);
    aq[gq][1] = *(const bf16x8*)(src + 32);
  }

  float l0 = 0.f, l1 = 0.f;
  f32x4 o0[4], o1[4];
#pragma unroll
  for (int n = 0; n < 4; n++) {
    o0[n] = {0.f, 0.f, 0.f, 0.f};
    o1[n] = {0.f, 0.f, 0.f, 0.f};
  }

  const float* mb_base = mbias + (size_t)b * 2048;
  unsigned* scw = SC[w];
  int sh[4];
#pragma unroll
  for (int r = 0; r < 4; r++) sh[r] = ((r + lr + 1) & 1) << 4;

  // ---- prologue: K[jt0]->Kb[0], V[jt0]->Vb[0]
#pragma unroll
  for (int i = 0; i < 2; i++) {
    int chunk = i * 4 + w;
    int row = chunk * 8 + srow;
    GLDS16(kgb + (size_t)(jt0 * 64 + row) * 64 + ((t16 ^ (row & 7)) * 8),
           Kb[0] + chunk * 512 + lane * 8);
  }
#pragma unroll
  for (int i = 0; i < 2; i++) {
    int chunk = i * 4 + w;
    int p = chunk * 8 + srow;
    GLDS16(vgb + jt0 * 64 + (size_t)p * 2048 + ((t16 ^ (p & 7)) * 8),
           Vb[0] + chunk * 512 + lane * 8);
  }
  __syncthreads();

  int lt = 0;
  for (int jt = jt0; jt < jt1; ++jt, ++lt) {
    const int j0 = jt * 64;
    const int cur = lt & 1;

    f32x4 mbv[4];
#pragma unroll
    for (int n = 0; n < 4; n++)
      mbv[n] = *(const f32x4*)&mb_base[j0 + n * 16 + g * 4];

    const bf16_t* rb0 = rgb + (size_t)j0 * 64;
    bf16x8 ar0[6];
#pragma unroll
    for (int fi = 0; fi < 6; fi++) {
      int f = 6 - 2 * w + fi;
      ar0[fi] = *(const bf16x8*)(rb0 + (size_t)(f * 16 + lr) * 64);
    }

    if (jt + 1 < jt1) {
#pragma unroll
      for (int i = 0; i < 2; i++) {
        int chunk = i * 4 + w;
        int p = chunk * 8 + srow;
        GLDS16(vgb + (j0 + 64) + (size_t)p * 2048 + ((t16 ^ (p & 7)) * 8),
               Vb[cur ^ 1] + chunk * 512 + lane * 8);
      }
      const bf16_t* kn = kgb + (size_t)(j0 + 64) * 64;
#pragma unroll
      for (int i = 0; i < 2; i++) {
        int chunk = i * 4 + w;
        int row = chunk * 8 + srow;
        GLDS16(kn + row * 64 + ((t16 ^ (row & 7)) * 8),
               Kb[cur ^ 1] + chunk * 512 + lane * 8);
      }
    }

    // ---- QK + rel band MFMAs
    f32x4 sacc0[4], sacc1[4], er0[5], er1[5];
#pragma unroll
    for (int n = 0; n < 4; n++) {
      sacc0[n] = {0.f, 0.f, 0.f, 0.f};
      sacc1[n] = {0.f, 0.f, 0.f, 0.f};
    }
#pragma unroll
    for (int n = 0; n < 5; n++) {
      er0[n] = {0.f, 0.f, 0.f, 0.f};
      er1[n] = {0.f, 0.f, 0.f, 0.f};
    }
    const bf16_t* kcur = Kb[cur];
    __builtin_amdgcn_s_setprio(1);
    {
      int cbs = lk ^ swz;
#pragma unroll
      for (int n = 0; n < 4; n++) {
        bf16x8 ak = *(const bf16x8*)&kcur[(n * 16 + lr) * 64 + cbs];
        sacc0[n] = mfma16(ak, aq[0][0], sacc0[n]);
        sacc1[n] = mfma16(ak, aq[1][0], sacc1[n]);
      }
    }
    bf16x8 ar1[6];
#pragma unroll
    for (int fi = 0; fi < 6; fi++) {
      int f = 6 - 2 * w + fi;
      ar1[fi] = *(const bf16x8*)(rb0 + 32 + (size_t)(f * 16 + lr) * 64);
    }
#pragma unroll
    for (int fi = 0; fi < 6; fi++) {
      if (fi >= 1) er0[fi - 1] = mfma16(ar0[fi], aq[0][0], er0[fi - 1]);
      if (fi <= 4) er1[fi] = mfma16(ar0[fi], aq[1][0], er1[fi]);
    }
    {
      int cbs = (32 + lk) ^ swz;
#pragma unroll
      for (int n = 0; n < 4; n++) {
        bf16x8 ak = *(const bf16x8*)&kcur[(n * 16 + lr) * 64 + cbs];
        sacc0[n] = mfma16(ak, aq[0][1], sacc0[n]);
        sacc1[n] = mfma16(ak, aq[1][1], sacc1[n]);
      }
    }
#pragma unroll
    for (int fi = 0; fi < 6; fi++) {
      if (fi >= 1) er0[fi - 1] = mfma16(ar1[fi], aq[0][1], er0[fi - 1]);
      if (fi <= 4) er1[fi] = mfma16(ar1[fi], aq[1][1], er1[fi]);
    }
    __builtin_amdgcn_s_setprio(0);

    // ---- softmax both groups (static max, in-lane only)
    bf16x8 bp0[2], bp1[2];
#pragma unroll
    for (int gq = 0; gq < 2; gq++) {
      f32x4* sacc = gq ? sacc1 : sacc0;
      f32x4* er = gq ? er1 : er0;
#pragma unroll
      for (int n2 = 0; n2 < 5; n2++) {
        uint2 u = {pack2(er[n2][0], er[n2][1]), pack2(er[n2][2], er[n2][3])};
        *(uint2*)&scw[lr * 42 + n2 * 8 + g * 2] = u;
      }
      float ps = 0.f;
      float e[4][4];
#pragma unroll
      for (int n = 0; n < 4; n++) {
#pragma unroll
        for (int r = 0; r < 4; r++) {
          int key = n * 16 + g * 4 + r;
          int idx = key - lr + 15;
          unsigned d = scw[lr * 42 + (idx >> 1)];
          float bias = __builtin_bit_cast(float, (d >> sh[r]) << 16);
          float s = sacc[n][r] + bias + mbv[n][r];
          e[n][r] = exp2f(s - MCONST);
          ps += e[n][r];
        }
      }
      if (gq) l1 += ps; else l0 += ps;
#pragma unroll
      for (int n = 0; n < 4; n++) {
        uint2 u = {pack2(e[n][0], e[n][1]), pack2(e[n][2], e[n][3])};
        *(uint2*)&scw[lr * 36 + n * 8 + g * 2] = u;
      }
      uint4 t0 = *(const uint4*)&scw[lr * 36 + g * 4];
      uint4 t1 = *(const uint4*)&scw[lr * 36 + 16 + g * 4];
      if (gq) {
        bp1[0] = __builtin_bit_cast(bf16x8, t0);
        bp1[1] = __builtin_bit_cast(bf16x8, t1);
      } else {
        bp0[0] = __builtin_bit_cast(bf16x8, t0);
        bp0[1] = __builtin_bit_cast(bf16x8, t1);
      }
    }

    // ---- ctx^T += V^T P
    const bf16_t* vcur = Vb[cur];
    __builtin_amdgcn_s_setprio(1);
#pragma unroll
    for (int kk = 0; kk < 2; kk++) {
      int cbs = (kk * 32 + lk) ^ swz;
#pragma unroll
      for (int n = 0; n < 4; n++) {
        bf16x8 av = *(const bf16x8*)&vcur[(n * 16 + lr) * 64 + cbs];
        o0[n] = mfma16(av, bp0[kk], o0[n]);
        o1[n] = mfma16(av, bp1[kk], o1[n]);
      }
    }
    __builtin_amdgcn_s_setprio(0);

    __syncthreads();  // single barrier: drains staging, orders buffer reuse
  }

  // ---- cross-group l reduction, write partials to this split's slices
  l0 += __shfl_xor(l0, 16, 64);
  l0 += __shfl_xor(l0, 32, 64);
  l1 += __shfl_xor(l1, 16, 64);
  l1 += __shfl_xor(l1, 32, 64);

  float* osl = octx + (size_t)sidx * 4096 * 1024;
  float* lsl = lbuf + (size_t)sidx * 2 * 16 * 2048;
#pragma unroll
  for (int gq = 0; gq < 2; gq++) {
    f32x4* o = gq ? o1 : o0;
    int q = i0 + w * 32 + gq * 16 + lr;
    if (g == 0) lsl[(size_t)bh * 2048 + q] = gq ? l1 : l0;
    float* dst = osl + ((size_t)b * 2048 + q) * 1024 + h * 64 + g * 4;
#pragma unroll
    for (int n = 0; n < 4; n++) *(f32x4*)(dst + n * 16) = o[n];
  }
}

// ---------------------------------------------------------------------------
extern "C" void kernel_launch(void* const* d_in, const int* in_sizes, int n_in,
                              void* d_out, int out_size, void* d_ws,
                              size_t ws_size, hipStream_t stream) {
  (void)in_sizes; (void)n_in; (void)out_size; (void)ws_size;
  const float* Q    = (const float*)d_in[0];
  const float* K    = (const float*)d_in[1];
  const float* V    = (const float*)d_in[2];
  const float* mask = (const float*)d_in[3];
  const float* WQ   = (const float*)d_in[4];
  const float* WK   = (const float*)d_in[5];
  const float* WV   = (const float*)d_in[6];
  const float* rel  = (const float*)d_in[7];
  const float* dW   = (const float*)d_in[8];
  const float* db   = (const float*)d_in[9];
  float* out = (float*)d_out;

  const size_t NQKV = (size_t)2 * 16 * 2048 * 64;  // 4,194,304
  bf16_t* qb   = (bf16_t*)d_ws;
  bf16_t* kb   = qb + NQKV;
  bf16_t* vb   = kb + NQKV;                    // V^T (b,h,p,t)
  bf16_t* relb = vb + NQKV;                    // 4096*64 bf16
  float*  mbias = (float*)(relb + 4096 * 64);  // 4096 f32
  float*  octx = mbias + 4096;                 // 3 x 4096*1024 f32
  float*  lbuf = octx + (size_t)3 * 4096 * 1024;  // 3 x 65536 f32

  dim3 blk(256);
  prep_kernel<<<dim3((4096 * 64 + 4096) / 256), blk, 0, stream>>>(rel, mask,
                                                                  relb, mbias);
  proj_gemm_kernel<<<dim3(32, 8, 3), blk, 0, stream>>>(Q, K, V, WQ, WK, WV, qb,
                                                       kb, vb);
  attn_kernel<<<dim3(1536), blk, 0, stream>>>(qb, kb, vb, relb, mbias, octx,
                                              lbuf);
  dense_gemm_kernel<<<dim3(32, 8), blk, 0, stream>>>(octx, lbuf, dW, db, out);
}

// Round 13
// 194.239 us; speedup vs baseline: 2.9429x; 2.4816x over previous
//
#include <hip/hip_runtime.h>
#include <hip/hip_bf16.h>

typedef __bf16 bf16_t;
typedef __bf16 bf16x2 __attribute__((ext_vector_type(2)));
typedef __bf16 bf16x8 __attribute__((ext_vector_type(8)));
typedef float f32x4 __attribute__((ext_vector_type(4)));

#define QSCALE 0.1803368801111396f   /* 0.125 * log2(e) */
#define MLOG2E 1.4426950408889634f
#define MCONST 12.0f                 /* static softmax max (log2 domain) */

__device__ __forceinline__ f32x4 mfma16(bf16x8 a, bf16x8 b, f32x4 c) {
  return __builtin_amdgcn_mfma_f32_16x16x32_bf16(a, b, c, 0, 0, 0);
}

#define GLDS16(gsrc, ldst)                                                     \
  __builtin_amdgcn_global_load_lds(                                            \
      (const __attribute__((address_space(1))) void*)(gsrc),                   \
      (__attribute__((address_space(3))) void*)(ldst), 16, 0, 0)

__device__ __forceinline__ unsigned pack2(float a, float b) {
  bf16x2 t = {(bf16_t)a, (bf16_t)b};
  return __builtin_bit_cast(unsigned, t);
}
__device__ __forceinline__ unsigned short bbits(bf16_t v) {
  return __builtin_bit_cast(unsigned short, v);
}

// ---------------------------------------------------------------------------
// conv: f32 -> bf16 for Q,K,V (4M each) and WQ,WK,WV,dW (1M each)
// ---------------------------------------------------------------------------
__global__ void conv_kernel(const float* __restrict__ Q,
                            const float* __restrict__ K,
                            const float* __restrict__ V,
                            const float* __restrict__ WQ,
                            const float* __restrict__ WK,
                            const float* __restrict__ WV,
                            const float* __restrict__ dW,
                            bf16_t* __restrict__ qf, bf16_t* __restrict__ kf,
                            bf16_t* __restrict__ vf, bf16_t* __restrict__ wqf,
                            bf16_t* __restrict__ wkf, bf16_t* __restrict__ wvf,
                            bf16_t* __restrict__ dwf) {
  const int y = blockIdx.y;
  const float* s;
  bf16_t* d;
  size_t n;
  switch (y) {
    case 0: s = Q;  d = qf;  n = 4194304; break;
    case 1: s = K;  d = kf;  n = 4194304; break;
    case 2: s = V;  d = vf;  n = 4194304; break;
    case 3: s = WQ; d = wqf; n = 1048576; break;
    case 4: s = WK; d = wkf; n = 1048576; break;
    case 5: s = WV; d = wvf; n = 1048576; break;
    default: s = dW; d = dwf; n = 1048576; break;
  }
  size_t i = ((size_t)blockIdx.x * 256 + threadIdx.x) * 8;
  if (i >= n) return;
  float4 a = *(const float4*)(s + i);
  float4 b = *(const float4*)(s + i + 4);
  uint4 u = {pack2(a.x, a.y), pack2(a.z, a.w), pack2(b.x, b.y),
             pack2(b.z, b.w)};
  *(uint4*)(d + i) = u;
}

// ---------------------------------------------------------------------------
// prep: rel f32(4095,64) -> bf16(4096,64); mbias = (1-mask)*-1e9*log2e
// ---------------------------------------------------------------------------
__global__ void prep_kernel(const float* __restrict__ rel,
                            const float* __restrict__ mask,
                            bf16_t* __restrict__ relb,
                            float* __restrict__ mbias) {
  int idx = blockIdx.x * 256 + threadIdx.x;
  if (idx < 4096 * 64) {
    int row = idx >> 6;
    int col = idx & 63;
    int sr = row > 4094 ? 4094 : row;
    relb[idx] = (bf16_t)rel[sr * 64 + col];
  } else {
    int j = idx - 4096 * 64;
    if (j < 4096) mbias[j] = (1.0f - mask[j]) * -1e9f * MLOG2E;
  }
}

// ---------------------------------------------------------------------------
// Fused projection GEMM (bf16 inputs): z=0 -> qb scaled, (b,h,t,p);
// z=1 -> kb (b,h,t,p); z=2 -> vb TRANSPOSED (b,h,p,t).
// ---------------------------------------------------------------------------
__global__ __launch_bounds__(256) void proj_gemm_kernel(
    const bf16_t* __restrict__ Qf, const bf16_t* __restrict__ Kf,
    const bf16_t* __restrict__ Vf, const bf16_t* __restrict__ WQf,
    const bf16_t* __restrict__ WKf, const bf16_t* __restrict__ WVf,
    bf16_t* __restrict__ qb, bf16_t* __restrict__ kb,
    bf16_t* __restrict__ vb) {
  const int z = blockIdx.z;
  const bf16_t* A = z == 0 ? Qf : (z == 1 ? Kf : Vf);
  const bf16_t* W = z == 0 ? WQf : (z == 1 ? WKf : WVf);
  bf16_t* out = z == 0 ? qb : (z == 1 ? kb : vb);
  const float scale = z == 0 ? QSCALE : 1.0f;

  __shared__ bf16_t As[128][72];
  __shared__ bf16_t Bs[128][72];
  const int tid = threadIdx.x;
  const int lane = tid & 63;
  const int wid = tid >> 6;
  const int wm = wid >> 1, wn = wid & 1;
  const int row0 = blockIdx.x * 128;
  const int col0 = blockIdx.y * 128;
  const int lr = lane & 15;
  const int lk = (lane >> 4) * 8;

  f32x4 acc[4][4];
#pragma unroll
  for (int m = 0; m < 4; m++)
#pragma unroll
    for (int n = 0; n < 4; n++) acc[m][n] = {0.f, 0.f, 0.f, 0.f};

  for (int kt = 0; kt < 1024; kt += 64) {
#pragma unroll
    for (int i = 0; i < 4; i++) {
      int c = tid + i * 256;
      int row = c >> 3;
      int k8 = (c & 7) * 8;
      *(uint4*)&As[row][k8] =
          *(const uint4*)(A + (size_t)(row0 + row) * 1024 + kt + k8);
    }
#pragma unroll
    for (int i = 0; i < 4; i++) {
      int c = tid + i * 256;
      int col = c & 127;
      int k8 = (c >> 7) * 8;
      int gcol = col0 + col;
      int h = gcol >> 6, p = gcol & 63;
      const bf16_t* src = W + (size_t)h * 65536 + (size_t)(kt + k8) * 64 + p;
      unsigned short b0 = bbits(src[0]), b1 = bbits(src[64]);
      unsigned short b2 = bbits(src[128]), b3 = bbits(src[192]);
      unsigned short b4 = bbits(src[256]), b5 = bbits(src[320]);
      unsigned short b6 = bbits(src[384]), b7 = bbits(src[448]);
      uint4 u = {(unsigned)b0 | ((unsigned)b1 << 16),
                 (unsigned)b2 | ((unsigned)b3 << 16),
                 (unsigned)b4 | ((unsigned)b5 << 16),
                 (unsigned)b6 | ((unsigned)b7 << 16)};
      *(uint4*)&Bs[col][k8] = u;
    }
    __syncthreads();
#pragma unroll
    for (int kk = 0; kk < 2; kk++) {
      bf16x8 af[4], bfr[4];
#pragma unroll
      for (int m = 0; m < 4; m++)
        af[m] = *(const bf16x8*)&As[wm * 64 + m * 16 + lr][kk * 32 + lk];
#pragma unroll
      for (int n = 0; n < 4; n++)
        bfr[n] = *(const bf16x8*)&Bs[wn * 64 + n * 16 + lr][kk * 32 + lk];
#pragma unroll
      for (int m = 0; m < 4; m++)
#pragma unroll
        for (int n = 0; n < 4; n++)
          acc[m][n] = mfma16(af[m], bfr[n], acc[m][n]);
    }
    __syncthreads();
  }
  const int rb = (lane >> 4) * 4;
#pragma unroll
  for (int m = 0; m < 4; m++) {
#pragma unroll
    for (int n = 0; n < 4; n++) {
      int col = col0 + wn * 64 + n * 16 + lr;
      int h = col >> 6, p = col & 63;
      int row_base = row0 + wm * 64 + m * 16 + rb;
      int b = row_base >> 11, t0 = row_base & 2047;
      if (z == 2) {
        uint2 u = {pack2(acc[m][n][0], acc[m][n][1]),
                   pack2(acc[m][n][2], acc[m][n][3])};
        *(uint2*)&out[(((size_t)(b * 16 + h) * 64 + p) * 2048) + t0] = u;
      } else {
#pragma unroll
        for (int r = 0; r < 4; r++) {
          out[(((size_t)(b * 16 + h) * 2048 + t0 + r) * 64) + p] =
              (bf16_t)(acc[m][n][r] * scale);
        }
      }
    }
  }
}

// ---------------------------------------------------------------------------
// Dense output GEMM: out = ctx(bf16) @ dwf(bf16) + bias
// ---------------------------------------------------------------------------
__global__ __launch_bounds__(256) void dense_gemm_kernel(
    const bf16_t* __restrict__ A, const bf16_t* __restrict__ W,
    const float* __restrict__ bias, float* __restrict__ out) {
  __shared__ bf16_t As[128][72];
  __shared__ bf16_t Bs[128][72];
  const int tid = threadIdx.x;
  const int lane = tid & 63;
  const int wid = tid >> 6;
  const int wm = wid >> 1, wn = wid & 1;
  const int row0 = blockIdx.x * 128;
  const int col0 = blockIdx.y * 128;
  const int lr = lane & 15;
  const int lk = (lane >> 4) * 8;

  f32x4 acc[4][4];
#pragma unroll
  for (int m = 0; m < 4; m++)
#pragma unroll
    for (int n = 0; n < 4; n++) acc[m][n] = {0.f, 0.f, 0.f, 0.f};

  for (int kt = 0; kt < 1024; kt += 64) {
#pragma unroll
    for (int i = 0; i < 4; i++) {
      int c = tid + i * 256;
      int row = c >> 3;
      int k8 = (c & 7) * 8;
      *(uint4*)&As[row][k8] =
          *(const uint4*)(A + (size_t)(row0 + row) * 1024 + kt + k8);
    }
#pragma unroll
    for (int i = 0; i < 4; i++) {
      int c = tid + i * 256;
      int col = c & 127;
      int k8 = (c >> 7) * 8;
      const bf16_t* src = W + (size_t)(kt + k8) * 1024 + col0 + col;
      unsigned short b0 = bbits(src[0]), b1 = bbits(src[1024]);
      unsigned short b2 = bbits(src[2048]), b3 = bbits(src[3072]);
      unsigned short b4 = bbits(src[4096]), b5 = bbits(src[5120]);
      unsigned short b6 = bbits(src[6144]), b7 = bbits(src[7168]);
      uint4 u = {(unsigned)b0 | ((unsigned)b1 << 16),
                 (unsigned)b2 | ((unsigned)b3 << 16),
                 (unsigned)b4 | ((unsigned)b5 << 16),
                 (unsigned)b6 | ((unsigned)b7 << 16)};
      *(uint4*)&Bs[col][k8] = u;
    }
    __syncthreads();
#pragma unroll
    for (int kk = 0; kk < 2; kk++) {
      bf16x8 af[4], bfr[4];
#pragma unroll
      for (int m = 0; m < 4; m++)
        af[m] = *(const bf16x8*)&As[wm * 64 + m * 16 + lr][kk * 32 + lk];
#pragma unroll
      for (int n = 0; n < 4; n++)
        bfr[n] = *(const bf16x8*)&Bs[wn * 64 + n * 16 + lr][kk * 32 + lk];
#pragma unroll
      for (int m = 0; m < 4; m++)
#pragma unroll
        for (int n = 0; n < 4; n++)
          acc[m][n] = mfma16(af[m], bfr[n], acc[m][n]);
    }
    __syncthreads();
  }
  const int rb = (lane >> 4) * 4;
#pragma unroll
  for (int m = 0; m < 4; m++) {
#pragma unroll
    for (int n = 0; n < 4; n++) {
      int col = col0 + wn * 64 + n * 16 + lr;
      float bv = bias[col];
#pragma unroll
      for (int r = 0; r < 4; r++) {
        int row = row0 + wm * 64 + m * 16 + rb + r;
        out[(size_t)row * 1024 + col] = acc[m][n][r] + bv;
      }
    }
  }
}

// ---------------------------------------------------------------------------
// Flash attention (R10 structure): swapped-operand, QBLK=128, single barrier
// per jt, static-max softmax.  New: softmax0 -> PV0 MFMAs overlap softmax1
// (V frags held in regs, loaded once).
// ---------------------------------------------------------------------------
__global__ __launch_bounds__(256, 2) void attn_kernel(
    const bf16_t* __restrict__ qg, const bf16_t* __restrict__ kg,
    const bf16_t* __restrict__ vt, const bf16_t* __restrict__ relb,
    const float* __restrict__ mbias, bf16_t* __restrict__ ctx) {
  __shared__ bf16_t Kb[2][64 * 64];  // 16 KB
  __shared__ bf16_t Vb[2][64 * 64];  // 16 KB
  __shared__ bf16_t Rr[4][64 * 64];  // 32 KB ring (64-row chunks)
  __shared__ unsigned SC[4][688];    // 11 KB per-wave EL/PL scratch

  const int tid = threadIdx.x;
  const int lane = tid & 63;
  const int w = tid >> 6;

  // XCD-bijective remap (512 = 8 x 64)
  const int id = blockIdx.x;
  const int id2 = (id & 7) * 64 + (id >> 3);
  const int it = id2 & 15;
  const int bh = id2 >> 4;
  const int h = bh & 15;
  const int b = bh >> 4;
  const int i0 = it * 128;

  const size_t base = ((size_t)bh) * 2048 * 64;
  const int lr = lane & 15;
  const int g = lane >> 4;
  const int lk = g * 8;
  const int srow = lane >> 3;
  const int t16 = lane & 7;
  const int swz = (lr & 7) << 3;

  const bf16_t* kgb = kg + base;
  const bf16_t* vgb = vt + base;
  const bf16_t* rgb = relb + (size_t)(1920 - i0) * 64;

  bf16x8 aq[2][2];
#pragma unroll
  for (int gq = 0; gq < 2; gq++) {
    const bf16_t* src =
        qg + base + (size_t)(i0 + w * 32 + gq * 16 + lr) * 64 + lk;
    aq[gq][0] = *(const bf16x8*)(src);
    aq[gq][1] = *(const bf16x8*)(src + 32);
  }

  float l0 = 0.f, l1 = 0.f;
  f32x4 o0[4], o1[4];
#pragma unroll
  for (int n = 0; n < 4; n++) {
    o0[n] = {0.f, 0.f, 0.f, 0.f};
    o1[n] = {0.f, 0.f, 0.f, 0.f};
  }

  const float* mb_base = mbias + (size_t)b * 2048;
  unsigned* scw = SC[w];
  int sh[4];
#pragma unroll
  for (int r = 0; r < 4; r++) sh[r] = ((r + lr + 1) & 1) << 4;

  // ---- prologue: K[0]->Kb[0], V[0]->Vb[0], R chunks 0,1,2
#pragma unroll
  for (int i = 0; i < 2; i++) {
    int chunk = i * 4 + w;
    int row = chunk * 8 + srow;
    GLDS16(kgb + row * 64 + ((t16 ^ (row & 7)) * 8),
           Kb[0] + chunk * 512 + lane * 8);
  }
#pragma unroll
  for (int i = 0; i < 2; i++) {
    int chunk = i * 4 + w;
    int p = chunk * 8 + srow;
    GLDS16(vgb + (size_t)p * 2048 + ((t16 ^ (p & 7)) * 8),
           Vb[0] + chunk * 512 + lane * 8);
  }
#pragma unroll
  for (int c = 0; c < 3; c++) {
#pragma unroll
    for (int i = 0; i < 2; i++) {
      int chunk = i * 4 + w;
      int row = chunk * 8 + srow;
      GLDS16(rgb + (size_t)(c * 64 + row) * 64 + ((t16 ^ (row & 7)) * 8),
             Rr[c] + chunk * 512 + lane * 8);
    }
  }
  __syncthreads();

  for (int jt = 0; jt < 32; jt++) {
    const int j0 = jt * 64;

    // ---- mask-bias loads first
    f32x4 mbv[4];
#pragma unroll
    for (int n = 0; n < 4; n++)
      mbv[n] = *(const f32x4*)&mb_base[j0 + n * 16 + g * 4];

    // ---- stage next tiles (drain at this phase's single barrier)
    if (jt < 31) {
#pragma unroll
      for (int i = 0; i < 2; i++) {
        int chunk = i * 4 + w;
        int p = chunk * 8 + srow;
        GLDS16(vgb + (j0 + 64) + (size_t)p * 2048 + ((t16 ^ (p & 7)) * 8),
               Vb[(jt + 1) & 1] + chunk * 512 + lane * 8);
      }
      const bf16_t* kn = kgb + (size_t)(j0 + 64) * 64;
      bf16_t* kd = Kb[(jt + 1) & 1];
#pragma unroll
      for (int i = 0; i < 2; i++) {
        int chunk = i * 4 + w;
        int row = chunk * 8 + srow;
        GLDS16(kn + row * 64 + ((t16 ^ (row & 7)) * 8),
               kd + chunk * 512 + lane * 8);
      }
      const bf16_t* rs = rgb + (size_t)(jt + 3) * 64 * 64;
      bf16_t* rd = Rr[(jt + 3) & 3];
#pragma unroll
      for (int i = 0; i < 2; i++) {
        int chunk = i * 4 + w;
        int row = chunk * 8 + srow;
        GLDS16(rs + row * 64 + ((t16 ^ (row & 7)) * 8),
               rd + chunk * 512 + lane * 8);
      }
    }

    // ---- QK + rel band, both groups share every operand read
    f32x4 sacc0[4], sacc1[4], er0[5], er1[5];
#pragma unroll
    for (int n = 0; n < 4; n++) {
      sacc0[n] = {0.f, 0.f, 0.f, 0.f};
      sacc1[n] = {0.f, 0.f, 0.f, 0.f};
    }
#pragma unroll
    for (int n = 0; n < 5; n++) {
      er0[n] = {0.f, 0.f, 0.f, 0.f};
      er1[n] = {0.f, 0.f, 0.f, 0.f};
    }
    const bf16_t* kcur = Kb[jt & 1];
    __builtin_amdgcn_s_setprio(1);
#pragma unroll
    for (int kk = 0; kk < 2; kk++) {
      int cbs = (kk * 32 + lk) ^ swz;
#pragma unroll
      for (int n = 0; n < 4; n++) {
        bf16x8 ak = *(const bf16x8*)&kcur[(n * 16 + lr) * 64 + cbs];
        sacc0[n] = mfma16(ak, aq[0][kk], sacc0[n]);
        sacc1[n] = mfma16(ak, aq[1][kk], sacc1[n]);
      }
#pragma unroll
      for (int fi = 0; fi < 6; fi++) {
        int f = 6 - 2 * w + fi;  // frag row index in window (0..11)
        const bf16_t* rc = Rr[(jt + (f >> 2)) & 3];
        bf16x8 ar = *(const bf16x8*)&rc[((f & 3) * 16 + lr) * 64 + cbs];
        if (fi >= 1) er0[fi - 1] = mfma16(ar, aq[0][kk], er0[fi - 1]);
        if (fi <= 4) er1[fi] = mfma16(ar, aq[1][kk], er1[fi]);
      }
    }
    __builtin_amdgcn_s_setprio(0);

    const bf16_t* vcur = Vb[jt & 1];
    bf16x8 av[2][4];

    // ---- group 0 softmax
    {
#pragma unroll
      for (int n2 = 0; n2 < 5; n2++) {
        uint2 u = {pack2(er0[n2][0], er0[n2][1]), pack2(er0[n2][2], er0[n2][3])};
        *(uint2*)&scw[lr * 42 + n2 * 8 + g * 2] = u;
      }
      float ps = 0.f;
      float e[4][4];
#pragma unroll
      for (int n = 0; n < 4; n++) {
#pragma unroll
        for (int r = 0; r < 4; r++) {
          int key = n * 16 + g * 4 + r;
          int idx = key - lr + 15;
          unsigned d = scw[lr * 42 + (idx >> 1)];
          float bias = __builtin_bit_cast(float, (d >> sh[r]) << 16);
          float s = sacc0[n][r] + bias + mbv[n][r];
          e[n][r] = exp2f(s - MCONST);
          ps += e[n][r];
        }
      }
      l0 += ps;
#pragma unroll
      for (int n = 0; n < 4; n++) {
        uint2 u = {pack2(e[n][0], e[n][1]), pack2(e[n][2], e[n][3])};
        *(uint2*)&scw[lr * 36 + n * 8 + g * 2] = u;
      }
      bf16x8 bp0[2];
      bp0[0] = __builtin_bit_cast(bf16x8, *(const uint4*)&scw[lr * 36 + g * 4]);
      bp0[1] =
          __builtin_bit_cast(bf16x8, *(const uint4*)&scw[lr * 36 + 16 + g * 4]);
      // load V frags once (reused by PV1)
#pragma unroll
      for (int kk = 0; kk < 2; kk++) {
        int cbs = (kk * 32 + lk) ^ swz;
#pragma unroll
        for (int n = 0; n < 4; n++)
          av[kk][n] = *(const bf16x8*)&vcur[(n * 16 + lr) * 64 + cbs];
      }
      // PV0 (MFMA pipe busy while group-1 softmax runs on VALU)
      __builtin_amdgcn_s_setprio(1);
#pragma unroll
      for (int kk = 0; kk < 2; kk++)
#pragma unroll
        for (int n = 0; n < 4; n++) o0[n] = mfma16(av[kk][n], bp0[kk], o0[n]);
      __builtin_amdgcn_s_setprio(0);
    }

    // ---- group 1 softmax (overlaps PV0 drain) + PV1
    {
#pragma unroll
      for (int n2 = 0; n2 < 5; n2++) {
        uint2 u = {pack2(er1[n2][0], er1[n2][1]), pack2(er1[n2][2], er1[n2][3])};
        *(uint2*)&scw[lr * 42 + n2 * 8 + g * 2] = u;
      }
      float ps = 0.f;
      float e[4][4];
#pragma unroll
      for (int n = 0; n < 4; n++) {
#pragma unroll
        for (int r = 0; r < 4; r++) {
          int key = n * 16 + g * 4 + r;
          int idx = key - lr + 15;
          unsigned d = scw[lr * 42 + (idx >> 1)];
          float bias = __builtin_bit_cast(float, (d >> sh[r]) << 16);
          float s = sacc1[n][r] + bias + mbv[n][r];
          e[n][r] = exp2f(s - MCONST);
          ps += e[n][r];
        }
      }
      l1 += ps;
#pragma unroll
      for (int n = 0; n < 4; n++) {
        uint2 u = {pack2(e[n][0], e[n][1]), pack2(e[n][2], e[n][3])};
        *(uint2*)&scw[lr * 36 + n * 8 + g * 2] = u;
      }
      bf16x8 bp1[2];
      bp1[0] = __builtin_bit_cast(bf16x8, *(const uint4*)&scw[lr * 36 + g * 4]);
      bp1[1] =
          __builtin_bit_cast(bf16x8, *(const uint4*)&scw[lr * 36 + 16 + g * 4]);
      __builtin_amdgcn_s_setprio(1);
#pragma unroll
      for (int kk = 0; kk < 2; kk++)
#pragma unroll
        for (int n = 0; n < 4; n++) o1[n] = mfma16(av[kk][n], bp1[kk], o1[n]);
      __builtin_amdgcn_s_setprio(0);
    }

    __syncthreads();  // single barrier: drains staging, orders buffer reuse
  }

  // ---- final cross-group l reduction (once per kernel)
  l0 += __shfl_xor(l0, 16, 64);
  l0 += __shfl_xor(l0, 32, 64);
  l1 += __shfl_xor(l1, 16, 64);
  l1 += __shfl_xor(l1, 32, 64);

  // ---- write ctx (bt, h*64+p): o rows are p, col (=lr) is query
#pragma unroll
  for (int gq = 0; gq < 2; gq++) {
    f32x4* o = gq ? o1 : o0;
    float inv = 1.0f / (gq ? l1 : l0);
    size_t bt = (size_t)b * 2048 + i0 + w * 32 + gq * 16 + lr;
#pragma unroll
    for (int n = 0; n < 4; n++) {
      uint2 u = {pack2(o[n][0] * inv, o[n][1] * inv),
                 pack2(o[n][2] * inv, o[n][3] * inv)};
      *(uint2*)&ctx[bt * 1024 + h * 64 + n * 16 + g * 4] = u;
    }
  }
}

// ---------------------------------------------------------------------------
extern "C" void kernel_launch(void* const* d_in, const int* in_sizes, int n_in,
                              void* d_out, int out_size, void* d_ws,
                              size_t ws_size, hipStream_t stream) {
  (void)in_sizes; (void)n_in; (void)out_size; (void)ws_size;
  const float* Q    = (const float*)d_in[0];
  const float* K    = (const float*)d_in[1];
  const float* V    = (const float*)d_in[2];
  const float* mask = (const float*)d_in[3];
  const float* WQ   = (const float*)d_in[4];
  const float* WK   = (const float*)d_in[5];
  const float* WV   = (const float*)d_in[6];
  const float* rel  = (const float*)d_in[7];
  const float* dW   = (const float*)d_in[8];
  const float* db   = (const float*)d_in[9];
  float* out = (float*)d_out;

  const size_t N4M = (size_t)4096 * 1024;  // 4,194,304
  const size_t N1M = (size_t)1024 * 1024;  // 1,048,576
  bf16_t* qf   = (bf16_t*)d_ws;
  bf16_t* kf   = qf + N4M;
  bf16_t* vf   = kf + N4M;
  bf16_t* wqf  = vf + N4M;
  bf16_t* wkf  = wqf + N1M;
  bf16_t* wvf  = wkf + N1M;
  bf16_t* dwf  = wvf + N1M;
  bf16_t* qb   = dwf + N1M;
  bf16_t* kb   = qb + N4M;
  bf16_t* vb   = kb + N4M;                     // V^T (b,h,p,t)
  bf16_t* ctxb = vb + N4M;
  bf16_t* relb = ctxb + N4M;                   // 4096*64 bf16
  float*  mbias = (float*)(relb + 4096 * 64);  // 4096 f32

  dim3 blk(256);
  conv_kernel<<<dim3(2048, 7), blk, 0, stream>>>(Q, K, V, WQ, WK, WV, dW, qf,
                                                 kf, vf, wqf, wkf, wvf, dwf);
  prep_kernel<<<dim3((4096 * 64 + 4096) / 256), blk, 0, stream>>>(rel, mask,
                                                                  relb, mbias);
  proj_gemm_kernel<<<dim3(32, 8, 3), blk, 0, stream>>>(qf, kf, vf, wqf, wkf,
                                                       wvf, qb, kb, vb);
  attn_kernel<<<dim3(512), blk, 0, stream>>>(qb, kb, vb, relb, mbias, ctxb);
  dense_gemm_kernel<<<dim3(32, 8), blk, 0, stream>>>(ctxb, dwf, db, out);
}

// Round 14
// 186.736 us; speedup vs baseline: 3.0612x; 1.0402x over previous
//
#include <hip/hip_runtime.h>
#include <hip/hip_bf16.h>

typedef __bf16 bf16_t;
typedef __bf16 bf16x2 __attribute__((ext_vector_type(2)));
typedef __bf16 bf16x8 __attribute__((ext_vector_type(8)));
typedef float f32x4 __attribute__((ext_vector_type(4)));

#define QSCALE 0.1803368801111396f   /* 0.125 * log2(e) */
#define MLOG2E 1.4426950408889634f
#define MCONST 12.0f                 /* static softmax max (log2 domain) */

__device__ __forceinline__ f32x4 mfma16(bf16x8 a, bf16x8 b, f32x4 c) {
  return __builtin_amdgcn_mfma_f32_16x16x32_bf16(a, b, c, 0, 0, 0);
}

#define GLDS16(gsrc, ldst)                                                     \
  __builtin_amdgcn_global_load_lds(                                            \
      (const __attribute__((address_space(1))) void*)(gsrc),                   \
      (__attribute__((address_space(3))) void*)(ldst), 16, 0, 0)

__device__ __forceinline__ unsigned pack2(float a, float b) {
  bf16x2 t = {(bf16_t)a, (bf16_t)b};
  return __builtin_bit_cast(unsigned, t);
}

// ---------------------------------------------------------------------------
// conv: f32 -> bf16 for Q,K,V (elementwise)
// ---------------------------------------------------------------------------
__global__ void conv_kernel(const float* __restrict__ Q,
                            const float* __restrict__ K,
                            const float* __restrict__ V,
                            bf16_t* __restrict__ qf, bf16_t* __restrict__ kf,
                            bf16_t* __restrict__ vf) {
  const int y = blockIdx.y;
  const float* s = y == 0 ? Q : (y == 1 ? K : V);
  bf16_t* d = y == 0 ? qf : (y == 1 ? kf : vf);
  size_t i = ((size_t)blockIdx.x * 256 + threadIdx.x) * 8;
  float4 a = *(const float4*)(s + i);
  float4 b = *(const float4*)(s + i + 4);
  uint4 u = {pack2(a.x, a.y), pack2(a.z, a.w), pack2(b.x, b.y),
             pack2(b.z, b.w)};
  *(uint4*)(d + i) = u;
}

// ---------------------------------------------------------------------------
// transpose W -> bf16 [col][k] row-major (stride 1024) via padded LDS tile.
// mat 0..2: WQ/WK/WV (h,1024,64) -> wt[(h*64+p)*1024 + k]
// mat 3   : dW (1024,1024)       -> dwt[(n)*1024 + k]
// ---------------------------------------------------------------------------
__global__ void transpose_w_kernel(const float* __restrict__ WQ,
                                   const float* __restrict__ WK,
                                   const float* __restrict__ WV,
                                   const float* __restrict__ dW,
                                   bf16_t* __restrict__ wqt,
                                   bf16_t* __restrict__ wkt,
                                   bf16_t* __restrict__ wvt,
                                   bf16_t* __restrict__ dwt) {
  __shared__ float tl[64][65];
  const int mat = blockIdx.y;
  const float* s = mat == 0 ? WQ : (mat == 1 ? WK : (mat == 2 ? WV : dW));
  bf16_t* d = mat == 0 ? wqt : (mat == 1 ? wkt : (mat == 2 ? wvt : dwt));
  const int tile = blockIdx.x;
  int row0, col0;
  size_t sstride;
  const float* sp;
  if (mat < 3) {
    int h = tile >> 4;
    row0 = (tile & 15) * 64;  // k-tile
    col0 = h * 64;            // p base
    sstride = 64;
    sp = s + (size_t)h * 65536 + (size_t)row0 * 64;
  } else {
    int nt = tile >> 4;
    row0 = (tile & 15) * 64;  // k-tile
    col0 = nt * 64;           // n base
    sstride = 1024;
    sp = s + (size_t)row0 * 1024 + (size_t)nt * 64;
  }
  const int t = threadIdx.x;
#pragma unroll
  for (int i = 0; i < 16; i++) {
    int lin = t + i * 256;
    int r = lin >> 6, c = lin & 63;
    tl[r][c] = sp[(size_t)r * sstride + c];
  }
  __syncthreads();
#pragma unroll
  for (int i = 0; i < 16; i++) {
    int lin = t + i * 256;
    int p = lin >> 6, k = lin & 63;
    d[(size_t)(col0 + p) * 1024 + row0 + k] = (bf16_t)tl[k][p];
  }
}

// ---------------------------------------------------------------------------
// prep: rel f32(4095,64) -> bf16(4096,64); mbias = (1-mask)*-1e9*log2e
// ---------------------------------------------------------------------------
__global__ void prep_kernel(const float* __restrict__ rel,
                            const float* __restrict__ mask,
                            bf16_t* __restrict__ relb,
                            float* __restrict__ mbias) {
  int idx = blockIdx.x * 256 + threadIdx.x;
  if (idx < 4096 * 64) {
    int row = idx >> 6;
    int col = idx & 63;
    int sr = row > 4094 ? 4094 : row;
    relb[idx] = (bf16_t)rel[sr * 64 + col];
  } else {
    int j = idx - 4096 * 64;
    if (j < 4096) mbias[j] = (1.0f - mask[j]) * -1e9f * MLOG2E;
  }
}

// ---------------------------------------------------------------------------
// Fused projection GEMM, m97-style GLDS16 staging on BOTH operands.
// A: bf16 [4096][1024]; B: wt bf16 [1024 cols][1024 k].
// z=0 -> qb scaled (b,h,t,p); z=1 -> kb; z=2 -> vb transposed (b,h,p,t).
// ---------------------------------------------------------------------------
__global__ __launch_bounds__(256) void proj_gemm_kernel(
    const bf16_t* __restrict__ Qf, const bf16_t* __restrict__ Kf,
    const bf16_t* __restrict__ Vf, const bf16_t* __restrict__ WQt,
    const bf16_t* __restrict__ WKt, const bf16_t* __restrict__ WVt,
    bf16_t* __restrict__ qb, bf16_t* __restrict__ kb,
    bf16_t* __restrict__ vb) {
  const int z = blockIdx.z;
  const bf16_t* A = z == 0 ? Qf : (z == 1 ? Kf : Vf);
  const bf16_t* Wt = z == 0 ? WQt : (z == 1 ? WKt : WVt);
  bf16_t* out = z == 0 ? qb : (z == 1 ? kb : vb);
  const float scale = z == 0 ? QSCALE : 1.0f;

  __shared__ bf16_t As[128 * 64];
  __shared__ bf16_t Bs[128 * 64];
  const int tid = threadIdx.x;
  const int lane = tid & 63;
  const int wid = tid >> 6;
  const int wm = wid >> 1, wn = wid & 1;
  const int row0 = blockIdx.x * 128;
  const int col0 = blockIdx.y * 128;
  const int lr = lane & 15;
  const int lk = (lane >> 4) * 8;
  const int srow = lane >> 3;
  const int t16 = lane & 7;
  const int swz = (lr & 7) << 3;

  f32x4 acc[4][4];
#pragma unroll
  for (int m = 0; m < 4; m++)
#pragma unroll
    for (int n = 0; n < 4; n++) acc[m][n] = {0.f, 0.f, 0.f, 0.f};

  for (int kt = 0; kt < 1024; kt += 64) {
#pragma unroll
    for (int i = 0; i < 4; i++) {
      int chunk = i * 4 + wid;
      int row = chunk * 8 + srow;
      int so = (t16 ^ (row & 7)) * 8;
      GLDS16(A + (size_t)(row0 + row) * 1024 + kt + so,
             As + chunk * 512 + lane * 8);
      GLDS16(Wt + (size_t)(col0 + row) * 1024 + kt + so,
             Bs + chunk * 512 + lane * 8);
    }
    __syncthreads();
#pragma unroll
    for (int kk = 0; kk < 2; kk++) {
      int cbs = (kk * 32 + lk) ^ swz;
      bf16x8 af[4], bfr[4];
#pragma unroll
      for (int m = 0; m < 4; m++)
        af[m] = *(const bf16x8*)&As[(wm * 64 + m * 16 + lr) * 64 + cbs];
#pragma unroll
      for (int n = 0; n < 4; n++)
        bfr[n] = *(const bf16x8*)&Bs[(wn * 64 + n * 16 + lr) * 64 + cbs];
#pragma unroll
      for (int m = 0; m < 4; m++)
#pragma unroll
        for (int n = 0; n < 4; n++)
          acc[m][n] = mfma16(af[m], bfr[n], acc[m][n]);
    }
    __syncthreads();
  }
  const int rb = (lane >> 4) * 4;
#pragma unroll
  for (int m = 0; m < 4; m++) {
#pragma unroll
    for (int n = 0; n < 4; n++) {
      int col = col0 + wn * 64 + n * 16 + lr;
      int h = col >> 6, p = col & 63;
      int row_base = row0 + wm * 64 + m * 16 + rb;
      int b = row_base >> 11, t0 = row_base & 2047;
      if (z == 2) {
        uint2 u = {pack2(acc[m][n][0], acc[m][n][1]),
                   pack2(acc[m][n][2], acc[m][n][3])};
        *(uint2*)&out[(((size_t)(b * 16 + h) * 64 + p) * 2048) + t0] = u;
      } else {
#pragma unroll
        for (int r = 0; r < 4; r++) {
          out[(((size_t)(b * 16 + h) * 2048 + t0 + r) * 64) + p] =
              (bf16_t)(acc[m][n][r] * scale);
        }
      }
    }
  }
}

// ---------------------------------------------------------------------------
// Dense output GEMM, GLDS16 staging: out = ctx(bf16) @ dwt^T + bias
// (dwt is [n][k] bf16 row-major)
// ---------------------------------------------------------------------------
__global__ __launch_bounds__(256) void dense_gemm_kernel(
    const bf16_t* __restrict__ A, const bf16_t* __restrict__ Wt,
    const float* __restrict__ bias, float* __restrict__ out) {
  __shared__ bf16_t As[128 * 64];
  __shared__ bf16_t Bs[128 * 64];
  const int tid = threadIdx.x;
  const int lane = tid & 63;
  const int wid = tid >> 6;
  const int wm = wid >> 1, wn = wid & 1;
  const int row0 = blockIdx.x * 128;
  const int col0 = blockIdx.y * 128;
  const int lr = lane & 15;
  const int lk = (lane >> 4) * 8;
  const int srow = lane >> 3;
  const int t16 = lane & 7;
  const int swz = (lr & 7) << 3;

  f32x4 acc[4][4];
#pragma unroll
  for (int m = 0; m < 4; m++)
#pragma unroll
    for (int n = 0; n < 4; n++) acc[m][n] = {0.f, 0.f, 0.f, 0.f};

  for (int kt = 0; kt < 1024; kt += 64) {
#pragma unroll
    for (int i = 0; i < 4; i++) {
      int chunk = i * 4 + wid;
      int row = chunk * 8 + srow;
      int so = (t16 ^ (row & 7)) * 8;
      GLDS16(A + (size_t)(row0 + row) * 1024 + kt + so,
             As + chunk * 512 + lane * 8);
      GLDS16(Wt + (size_t)(col0 + row) * 1024 + kt + so,
             Bs + chunk * 512 + lane * 8);
    }
    __syncthreads();
#pragma unroll
    for (int kk = 0; kk < 2; kk++) {
      int cbs = (kk * 32 + lk) ^ swz;
      bf16x8 af[4], bfr[4];
#pragma unroll
      for (int m = 0; m < 4; m++)
        af[m] = *(const bf16x8*)&As[(wm * 64 + m * 16 + lr) * 64 + cbs];
#pragma unroll
      for (int n = 0; n < 4; n++)
        bfr[n] = *(const bf16x8*)&Bs[(wn * 64 + n * 16 + lr) * 64 + cbs];
#pragma unroll
      for (int m = 0; m < 4; m++)
#pragma unroll
        for (int n = 0; n < 4; n++)
          acc[m][n] = mfma16(af[m], bfr[n], acc[m][n]);
    }
    __syncthreads();
  }
  const int rb = (lane >> 4) * 4;
#pragma unroll
  for (int m = 0; m < 4; m++) {
#pragma unroll
    for (int n = 0; n < 4; n++) {
      int col = col0 + wn * 64 + n * 16 + lr;
      float bv = bias[col];
#pragma unroll
      for (int r = 0; r < 4; r++) {
        int row = row0 + wm * 64 + m * 16 + rb + r;
        out[(size_t)row * 1024 + col] = acc[m][n][r] + bv;
      }
    }
  }
}

// ---------------------------------------------------------------------------
// Flash attention (R13 structure, unchanged): swapped-operand, QBLK=128,
// single barrier per jt, static-max softmax, PV0 overlaps softmax1.
// ---------------------------------------------------------------------------
__global__ __launch_bounds__(256, 2) void attn_kernel(
    const bf16_t* __restrict__ qg, const bf16_t* __restrict__ kg,
    const bf16_t* __restrict__ vt, const bf16_t* __restrict__ relb,
    const float* __restrict__ mbias, bf16_t* __restrict__ ctx) {
  __shared__ bf16_t Kb[2][64 * 64];  // 16 KB
  __shared__ bf16_t Vb[2][64 * 64];  // 16 KB
  __shared__ bf16_t Rr[4][64 * 64];  // 32 KB ring (64-row chunks)
  __shared__ unsigned SC[4][688];    // 11 KB per-wave EL/PL scratch

  const int tid = threadIdx.x;
  const int lane = tid & 63;
  const int w = tid >> 6;

  const int id = blockIdx.x;
  const int id2 = (id & 7) * 64 + (id >> 3);
  const int it = id2 & 15;
  const int bh = id2 >> 4;
  const int h = bh & 15;
  const int b = bh >> 4;
  const int i0 = it * 128;

  const size_t base = ((size_t)bh) * 2048 * 64;
  const int lr = lane & 15;
  const int g = lane >> 4;
  const int lk = g * 8;
  const int srow = lane >> 3;
  const int t16 = lane & 7;
  const int swz = (lr & 7) << 3;

  const bf16_t* kgb = kg + base;
  const bf16_t* vgb = vt + base;
  const bf16_t* rgb = relb + (size_t)(1920 - i0) * 64;

  bf16x8 aq[2][2];
#pragma unroll
  for (int gq = 0; gq < 2; gq++) {
    const bf16_t* src =
        qg + base + (size_t)(i0 + w * 32 + gq * 16 + lr) * 64 + lk;
    aq[gq][0] = *(const bf16x8*)(src);
    aq[gq][1] = *(const bf16x8*)(src + 32);
  }

  float l0 = 0.f, l1 = 0.f;
  f32x4 o0[4], o1[4];
#pragma unroll
  for (int n = 0; n < 4; n++) {
    o0[n] = {0.f, 0.f, 0.f, 0.f};
    o1[n] = {0.f, 0.f, 0.f, 0.f};
  }

  const float* mb_base = mbias + (size_t)b * 2048;
  unsigned* scw = SC[w];
  int sh[4];
#pragma unroll
  for (int r = 0; r < 4; r++) sh[r] = ((r + lr + 1) & 1) << 4;

#pragma unroll
  for (int i = 0; i < 2; i++) {
    int chunk = i * 4 + w;
    int row = chunk * 8 + srow;
    GLDS16(kgb + row * 64 + ((t16 ^ (row & 7)) * 8),
           Kb[0] + chunk * 512 + lane * 8);
  }
#pragma unroll
  for (int i = 0; i < 2; i++) {
    int chunk = i * 4 + w;
    int p = chunk * 8 + srow;
    GLDS16(vgb + (size_t)p * 2048 + ((t16 ^ (p & 7)) * 8),
           Vb[0] + chunk * 512 + lane * 8);
  }
#pragma unroll
  for (int c = 0; c < 3; c++) {
#pragma unroll
    for (int i = 0; i < 2; i++) {
      int chunk = i * 4 + w;
      int row = chunk * 8 + srow;
      GLDS16(rgb + (size_t)(c * 64 + row) * 64 + ((t16 ^ (row & 7)) * 8),
             Rr[c] + chunk * 512 + lane * 8);
    }
  }
  __syncthreads();

  for (int jt = 0; jt < 32; jt++) {
    const int j0 = jt * 64;

    f32x4 mbv[4];
#pragma unroll
    for (int n = 0; n < 4; n++)
      mbv[n] = *(const f32x4*)&mb_base[j0 + n * 16 + g * 4];

    if (jt < 31) {
#pragma unroll
      for (int i = 0; i < 2; i++) {
        int chunk = i * 4 + w;
        int p = chunk * 8 + srow;
        GLDS16(vgb + (j0 + 64) + (size_t)p * 2048 + ((t16 ^ (p & 7)) * 8),
               Vb[(jt + 1) & 1] + chunk * 512 + lane * 8);
      }
      const bf16_t* kn = kgb + (size_t)(j0 + 64) * 64;
      bf16_t* kd = Kb[(jt + 1) & 1];
#pragma unroll
      for (int i = 0; i < 2; i++) {
        int chunk = i * 4 + w;
        int row = chunk * 8 + srow;
        GLDS16(kn + row * 64 + ((t16 ^ (row & 7)) * 8),
               kd + chunk * 512 + lane * 8);
      }
      const bf16_t* rs = rgb + (size_t)(jt + 3) * 64 * 64;
      bf16_t* rd = Rr[(jt + 3) & 3];
#pragma unroll
      for (int i = 0; i < 2; i++) {
        int chunk = i * 4 + w;
        int row = chunk * 8 + srow;
        GLDS16(rs + row * 64 + ((t16 ^ (row & 7)) * 8),
               rd + chunk * 512 + lane * 8);
      }
    }

    f32x4 sacc0[4], sacc1[4], er0[5], er1[5];
#pragma unroll
    for (int n = 0; n < 4; n++) {
      sacc0[n] = {0.f, 0.f, 0.f, 0.f};
      sacc1[n] = {0.f, 0.f, 0.f, 0.f};
    }
#pragma unroll
    for (int n = 0; n < 5; n++) {
      er0[n] = {0.f, 0.f, 0.f, 0.f};
      er1[n] = {0.f, 0.f, 0.f, 0.f};
    }
    const bf16_t* kcur = Kb[jt & 1];
    __builtin_amdgcn_s_setprio(1);
#pragma unroll
    for (int kk = 0; kk < 2; kk++) {
      int cbs = (kk * 32 + lk) ^ swz;
#pragma unroll
      for (int n = 0; n < 4; n++) {
        bf16x8 ak = *(const bf16x8*)&kcur[(n * 16 + lr) * 64 + cbs];
        sacc0[n] = mfma16(ak, aq[0][kk], sacc0[n]);
        sacc1[n] = mfma16(ak, aq[1][kk], sacc1[n]);
      }
#pragma unroll
      for (int fi = 0; fi < 6; fi++) {
        int f = 6 - 2 * w + fi;
        const bf16_t* rc = Rr[(jt + (f >> 2)) & 3];
        bf16x8 ar = *(const bf16x8*)&rc[((f & 3) * 16 + lr) * 64 + cbs];
        if (fi >= 1) er0[fi - 1] = mfma16(ar, aq[0][kk], er0[fi - 1]);
        if (fi <= 4) er1[fi] = mfma16(ar, aq[1][kk], er1[fi]);
      }
    }
    __builtin_amdgcn_s_setprio(0);

    const bf16_t* vcur = Vb[jt & 1];
    bf16x8 av[2][4];

    {
#pragma unroll
      for (int n2 = 0; n2 < 5; n2++) {
        uint2 u = {pack2(er0[n2][0], er0[n2][1]), pack2(er0[n2][2], er0[n2][3])};
        *(uint2*)&scw[lr * 42 + n2 * 8 + g * 2] = u;
      }
      float ps = 0.f;
      float e[4][4];
#pragma unroll
      for (int n = 0; n < 4; n++) {
#pragma unroll
        for (int r = 0; r < 4; r++) {
          int key = n * 16 + g * 4 + r;
          int idx = key - lr + 15;
          unsigned d = scw[lr * 42 + (idx >> 1)];
          float bias = __builtin_bit_cast(float, (d >> sh[r]) << 16);
          float s = sacc0[n][r] + bias + mbv[n][r];
          e[n][r] = exp2f(s - MCONST);
          ps += e[n][r];
        }
      }
      l0 += ps;
#pragma unroll
      for (int n = 0; n < 4; n++) {
        uint2 u = {pack2(e[n][0], e[n][1]), pack2(e[n][2], e[n][3])};
        *(uint2*)&scw[lr * 36 + n * 8 + g * 2] = u;
      }
      bf16x8 bp0[2];
      bp0[0] = __builtin_bit_cast(bf16x8, *(const uint4*)&scw[lr * 36 + g * 4]);
      bp0[1] =
          __builtin_bit_cast(bf16x8, *(const uint4*)&scw[lr * 36 + 16 + g * 4]);
#pragma unroll
      for (int kk = 0; kk < 2; kk++) {
        int cbs = (kk * 32 + lk) ^ swz;
#pragma unroll
        for (int n = 0; n < 4; n++)
          av[kk][n] = *(const bf16x8*)&vcur[(n * 16 + lr) * 64 + cbs];
      }
      __builtin_amdgcn_s_setprio(1);
#pragma unroll
      for (int kk = 0; kk < 2; kk++)
#pragma unroll
        for (int n = 0; n < 4; n++) o0[n] = mfma16(av[kk][n], bp0[kk], o0[n]);
      __builtin_amdgcn_s_setprio(0);
    }

    {
#pragma unroll
      for (int n2 = 0; n2 < 5; n2++) {
        uint2 u = {pack2(er1[n2][0], er1[n2][1]), pack2(er1[n2][2], er1[n2][3])};
        *(uint2*)&scw[lr * 42 + n2 * 8 + g * 2] = u;
      }
      float ps = 0.f;
      float e[4][4];
#pragma unroll
      for (int n = 0; n < 4; n++) {
#pragma unroll
        for (int r = 0; r < 4; r++) {
          int key = n * 16 + g * 4 + r;
          int idx = key - lr + 15;
          unsigned d = scw[lr * 42 + (idx >> 1)];
          float bias = __builtin_bit_cast(float, (d >> sh[r]) << 16);
          float s = sacc1[n][r] + bias + mbv[n][r];
          e[n][r] = exp2f(s - MCONST);
          ps += e[n][r];
        }
      }
      l1 += ps;
#pragma unroll
      for (int n = 0; n < 4; n++) {
        uint2 u = {pack2(e[n][0], e[n][1]), pack2(e[n][2], e[n][3])};
        *(uint2*)&scw[lr * 36 + n * 8 + g * 2] = u;
      }
      bf16x8 bp1[2];
      bp1[0] = __builtin_bit_cast(bf16x8, *(const uint4*)&scw[lr * 36 + g * 4]);
      bp1[1] =
          __builtin_bit_cast(bf16x8, *(const uint4*)&scw[lr * 36 + 16 + g * 4]);
      __builtin_amdgcn_s_setprio(1);
#pragma unroll
      for (int kk = 0; kk < 2; kk++)
#pragma unroll
        for (int n = 0; n < 4; n++) o1[n] = mfma16(av[kk][n], bp1[kk], o1[n]);
      __builtin_amdgcn_s_setprio(0);
    }

    __syncthreads();
  }

  l0 += __shfl_xor(l0, 16, 64);
  l0 += __shfl_xor(l0, 32, 64);
  l1 += __shfl_xor(l1, 16, 64);
  l1 += __shfl_xor(l1, 32, 64);

#pragma unroll
  for (int gq = 0; gq < 2; gq++) {
    f32x4* o = gq ? o1 : o0;
    float inv = 1.0f / (gq ? l1 : l0);
    size_t bt = (size_t)b * 2048 + i0 + w * 32 + gq * 16 + lr;
#pragma unroll
    for (int n = 0; n < 4; n++) {
      uint2 u = {pack2(o[n][0] * inv, o[n][1] * inv),
                 pack2(o[n][2] * inv, o[n][3] * inv)};
      *(uint2*)&ctx[bt * 1024 + h * 64 + n * 16 + g * 4] = u;
    }
  }
}

// ---------------------------------------------------------------------------
extern "C" void kernel_launch(void* const* d_in, const int* in_sizes, int n_in,
                              void* d_out, int out_size, void* d_ws,
                              size_t ws_size, hipStream_t stream) {
  (void)in_sizes; (void)n_in; (void)out_size; (void)ws_size;
  const float* Q    = (const float*)d_in[0];
  const float* K    = (const float*)d_in[1];
  const float* V    = (const float*)d_in[2];
  const float* mask = (const float*)d_in[3];
  const float* WQ   = (const float*)d_in[4];
  const float* WK   = (const float*)d_in[5];
  const float* WV   = (const float*)d_in[6];
  const float* rel  = (const float*)d_in[7];
  const float* dW   = (const float*)d_in[8];
  const float* db   = (const float*)d_in[9];
  float* out = (float*)d_out;

  const size_t N4M = (size_t)4096 * 1024;
  const size_t N1M = (size_t)1024 * 1024;
  bf16_t* qf   = (bf16_t*)d_ws;
  bf16_t* kf   = qf + N4M;
  bf16_t* vf   = kf + N4M;
  bf16_t* wqt  = vf + N4M;
  bf16_t* wkt  = wqt + N1M;
  bf16_t* wvt  = wkt + N1M;
  bf16_t* dwt  = wvt + N1M;
  bf16_t* qb   = dwt + N1M;
  bf16_t* kb   = qb + N4M;
  bf16_t* vb   = kb + N4M;                     // V^T (b,h,p,t)
  bf16_t* ctxb = vb + N4M;
  bf16_t* relb = ctxb + N4M;                   // 4096*64 bf16
  float*  mbias = (float*)(relb + 4096 * 64);  // 4096 f32

  dim3 blk(256);
  conv_kernel<<<dim3(2048, 3), blk, 0, stream>>>(Q, K, V, qf, kf, vf);
  transpose_w_kernel<<<dim3(256, 4), blk, 0, stream>>>(WQ, WK, WV, dW, wqt,
                                                       wkt, wvt, dwt);
  prep_kernel<<<dim3((4096 * 64 + 4096) / 256), blk, 0, stream>>>(rel, mask,
                                                                  relb, mbias);
  proj_gemm_kernel<<<dim3(32, 8, 3), blk, 0, stream>>>(qf, kf, vf, wqt, wkt,
                                                       wvt, qb, kb, vb);
  attn_kernel<<<dim3(512), blk, 0, stream>>>(qb, kb, vb, relb, mbias, ctxb);
  dense_gemm_kernel<<<dim3(32, 8), blk, 0, stream>>>(ctxb, dwt, db, out);
}

// Round 15
// 181.278 us; speedup vs baseline: 3.1533x; 1.0301x over previous
//
#include <hip/hip_runtime.h>
#include <hip/hip_bf16.h>

typedef __bf16 bf16_t;
typedef __bf16 bf16x2 __attribute__((ext_vector_type(2)));
typedef __bf16 bf16x8 __attribute__((ext_vector_type(8)));
typedef float f32x4 __attribute__((ext_vector_type(4)));

#define QSCALE 0.1803368801111396f   /* 0.125 * log2(e) */
#define MLOG2E 1.4426950408889634f
#define MCONST 12.0f                 /* static softmax max (log2 domain) */

__device__ __forceinline__ f32x4 mfma16(bf16x8 a, bf16x8 b, f32x4 c) {
  return __builtin_amdgcn_mfma_f32_16x16x32_bf16(a, b, c, 0, 0, 0);
}

#define GLDS16(gsrc, ldst)                                                     \
  __builtin_amdgcn_global_load_lds(                                            \
      (const __attribute__((address_space(1))) void*)(gsrc),                   \
      (__attribute__((address_space(3))) void*)(ldst), 16, 0, 0)

__device__ __forceinline__ unsigned pack2(float a, float b) {
  bf16x2 t = {(bf16_t)a, (bf16_t)b};
  return __builtin_bit_cast(unsigned, t);
}

// ---------------------------------------------------------------------------
// transpose W -> bf16 [col][k] row-major (stride 1024) via padded LDS tile.
// mat 0..2: WQ/WK/WV (h,1024,64) -> wt[(h*64+p)*1024 + k]
// mat 3   : dW (1024,1024)       -> dwt[(n)*1024 + k]
// ---------------------------------------------------------------------------
__global__ void transpose_w_kernel(const float* __restrict__ WQ,
                                   const float* __restrict__ WK,
                                   const float* __restrict__ WV,
                                   const float* __restrict__ dW,
                                   bf16_t* __restrict__ wqt,
                                   bf16_t* __restrict__ wkt,
                                   bf16_t* __restrict__ wvt,
                                   bf16_t* __restrict__ dwt) {
  __shared__ float tl[64][65];
  const int mat = blockIdx.y;
  const float* s = mat == 0 ? WQ : (mat == 1 ? WK : (mat == 2 ? WV : dW));
  bf16_t* d = mat == 0 ? wqt : (mat == 1 ? wkt : (mat == 2 ? wvt : dwt));
  const int tile = blockIdx.x;
  int row0, col0;
  size_t sstride;
  const float* sp;
  if (mat < 3) {
    int h = tile >> 4;
    row0 = (tile & 15) * 64;  // k-tile
    col0 = h * 64;            // p base
    sstride = 64;
    sp = s + (size_t)h * 65536 + (size_t)row0 * 64;
  } else {
    int nt = tile >> 4;
    row0 = (tile & 15) * 64;  // k-tile
    col0 = nt * 64;           // n base
    sstride = 1024;
    sp = s + (size_t)row0 * 1024 + (size_t)nt * 64;
  }
  const int t = threadIdx.x;
#pragma unroll
  for (int i = 0; i < 16; i++) {
    int lin = t + i * 256;
    int r = lin >> 6, c = lin & 63;
    tl[r][c] = sp[(size_t)r * sstride + c];
  }
  __syncthreads();
#pragma unroll
  for (int i = 0; i < 16; i++) {
    int lin = t + i * 256;
    int p = lin >> 6, k = lin & 63;
    d[(size_t)(col0 + p) * 1024 + row0 + k] = (bf16_t)tl[k][p];
  }
}

// ---------------------------------------------------------------------------
// prep: rel f32(4095,64) -> bf16(4096,64); mbias = (1-mask)*-1e9*log2e
// ---------------------------------------------------------------------------
__global__ void prep_kernel(const float* __restrict__ rel,
                            const float* __restrict__ mask,
                            bf16_t* __restrict__ relb,
                            float* __restrict__ mbias) {
  int idx = blockIdx.x * 256 + threadIdx.x;
  if (idx < 4096 * 64) {
    int row = idx >> 6;
    int col = idx & 63;
    int sr = row > 4094 ? 4094 : row;
    relb[idx] = (bf16_t)rel[sr * 64 + col];
  } else {
    int j = idx - 4096 * 64;
    if (j < 4096) mbias[j] = (1.0f - mask[j]) * -1e9f * MLOG2E;
  }
}

// ---------------------------------------------------------------------------
// Fused projection GEMM: A staged from f32 with fused pack2 (swizzled LDS
// write matches GLDS16-read layout); W staged via GLDS16 (bf16, transposed).
// z=0 -> qb scaled (b,h,t,p); z=1 -> kb; z=2 -> vb transposed (b,h,p,t).
// ---------------------------------------------------------------------------
__global__ __launch_bounds__(256) void proj_gemm_kernel(
    const float* __restrict__ Q, const float* __restrict__ K,
    const float* __restrict__ V, const bf16_t* __restrict__ WQt,
    const bf16_t* __restrict__ WKt, const bf16_t* __restrict__ WVt,
    bf16_t* __restrict__ qb, bf16_t* __restrict__ kb,
    bf16_t* __restrict__ vb) {
  const int z = blockIdx.z;
  const float* A = z == 0 ? Q : (z == 1 ? K : V);
  const bf16_t* Wt = z == 0 ? WQt : (z == 1 ? WKt : WVt);
  bf16_t* out = z == 0 ? qb : (z == 1 ? kb : vb);
  const float scale = z == 0 ? QSCALE : 1.0f;

  __shared__ bf16_t As[128 * 64];
  __shared__ bf16_t Bs[128 * 64];
  const int tid = threadIdx.x;
  const int lane = tid & 63;
  const int wid = tid >> 6;
  const int wm = wid >> 1, wn = wid & 1;
  const int row0 = blockIdx.x * 128;
  const int col0 = blockIdx.y * 128;
  const int lr = lane & 15;
  const int lk = (lane >> 4) * 8;
  const int srow = lane >> 3;
  const int t16 = lane & 7;
  const int swz = (lr & 7) << 3;

  f32x4 acc[4][4];
#pragma unroll
  for (int m = 0; m < 4; m++)
#pragma unroll
    for (int n = 0; n < 4; n++) acc[m][n] = {0.f, 0.f, 0.f, 0.f};

  for (int kt = 0; kt < 1024; kt += 64) {
    // W: GLDS16 with pre-swizzled source
#pragma unroll
    for (int i = 0; i < 4; i++) {
      int chunk = i * 4 + wid;
      int row = chunk * 8 + srow;
      int so = (t16 ^ (row & 7)) * 8;
      GLDS16(Wt + (size_t)(col0 + row) * 1024 + kt + so,
             Bs + chunk * 512 + lane * 8);
    }
    // A: f32 load + pack to bf16, swizzled ds_write (matches read layout)
#pragma unroll
    for (int i = 0; i < 4; i++) {
      int c = tid + i * 256;
      int row = c >> 3;
      int k8 = (c & 7) * 8;
      const float* src = A + (size_t)(row0 + row) * 1024 + kt + k8;
      float4 v0 = *(const float4*)(src);
      float4 v1 = *(const float4*)(src + 4);
      uint4 u = {pack2(v0.x, v0.y), pack2(v0.z, v0.w), pack2(v1.x, v1.y),
                 pack2(v1.z, v1.w)};
      *(uint4*)&As[row * 64 + (k8 ^ ((row & 7) << 3))] = u;
    }
    __syncthreads();
#pragma unroll
    for (int kk = 0; kk < 2; kk++) {
      int cbs = (kk * 32 + lk) ^ swz;
      bf16x8 af[4], bfr[4];
#pragma unroll
      for (int m = 0; m < 4; m++)
        af[m] = *(const bf16x8*)&As[(wm * 64 + m * 16 + lr) * 64 + cbs];
#pragma unroll
      for (int n = 0; n < 4; n++)
        bfr[n] = *(const bf16x8*)&Bs[(wn * 64 + n * 16 + lr) * 64 + cbs];
#pragma unroll
      for (int m = 0; m < 4; m++)
#pragma unroll
        for (int n = 0; n < 4; n++)
          acc[m][n] = mfma16(af[m], bfr[n], acc[m][n]);
    }
    __syncthreads();
  }
  const int rb = (lane >> 4) * 4;
#pragma unroll
  for (int m = 0; m < 4; m++) {
#pragma unroll
    for (int n = 0; n < 4; n++) {
      int col = col0 + wn * 64 + n * 16 + lr;
      int h = col >> 6, p = col & 63;
      int row_base = row0 + wm * 64 + m * 16 + rb;
      int b = row_base >> 11, t0 = row_base & 2047;
      if (z == 2) {
        uint2 u = {pack2(acc[m][n][0], acc[m][n][1]),
                   pack2(acc[m][n][2], acc[m][n][3])};
        *(uint2*)&out[(((size_t)(b * 16 + h) * 64 + p) * 2048) + t0] = u;
      } else {
#pragma unroll
        for (int r = 0; r < 4; r++) {
          out[(((size_t)(b * 16 + h) * 2048 + t0 + r) * 64) + p] =
              (bf16_t)(acc[m][n][r] * scale);
        }
      }
    }
  }
}

// ---------------------------------------------------------------------------
// Dense output GEMM, 128x64 tiles (grid 32x16 -> 2 blocks/CU):
// out = ctx(bf16) @ dwt^T + bias  (dwt is [n][k] bf16 row-major)
// Wave wid owns rows wid*32..+32, all 64 cols.
// ---------------------------------------------------------------------------
__global__ __launch_bounds__(256) void dense_gemm_kernel(
    const bf16_t* __restrict__ A, const bf16_t* __restrict__ Wt,
    const float* __restrict__ bias, float* __restrict__ out) {
  __shared__ bf16_t As[128 * 64];  // 16 KB
  __shared__ bf16_t Bs[64 * 64];   //  8 KB
  const int tid = threadIdx.x;
  const int lane = tid & 63;
  const int wid = tid >> 6;
  const int row0 = blockIdx.x * 128;
  const int col0 = blockIdx.y * 64;
  const int lr = lane & 15;
  const int lk = (lane >> 4) * 8;
  const int srow = lane >> 3;
  const int t16 = lane & 7;
  const int swz = (lr & 7) << 3;

  f32x4 acc[2][4];
#pragma unroll
  for (int m = 0; m < 2; m++)
#pragma unroll
    for (int n = 0; n < 4; n++) acc[m][n] = {0.f, 0.f, 0.f, 0.f};

  for (int kt = 0; kt < 1024; kt += 64) {
#pragma unroll
    for (int i = 0; i < 4; i++) {
      int chunk = i * 4 + wid;
      int row = chunk * 8 + srow;
      int so = (t16 ^ (row & 7)) * 8;
      GLDS16(A + (size_t)(row0 + row) * 1024 + kt + so,
             As + chunk * 512 + lane * 8);
    }
#pragma unroll
    for (int i = 0; i < 2; i++) {
      int chunk = i * 4 + wid;
      int row = chunk * 8 + srow;
      int so = (t16 ^ (row & 7)) * 8;
      GLDS16(Wt + (size_t)(col0 + row) * 1024 + kt + so,
             Bs + chunk * 512 + lane * 8);
    }
    __syncthreads();
#pragma unroll
    for (int kk = 0; kk < 2; kk++) {
      int cbs = (kk * 32 + lk) ^ swz;
      bf16x8 af[2], bfr[4];
#pragma unroll
      for (int m = 0; m < 2; m++)
        af[m] = *(const bf16x8*)&As[(wid * 32 + m * 16 + lr) * 64 + cbs];
#pragma unroll
      for (int n = 0; n < 4; n++)
        bfr[n] = *(const bf16x8*)&Bs[(n * 16 + lr) * 64 + cbs];
#pragma unroll
      for (int m = 0; m < 2; m++)
#pragma unroll
        for (int n = 0; n < 4; n++)
          acc[m][n] = mfma16(af[m], bfr[n], acc[m][n]);
    }
    __syncthreads();
  }
  const int rb = (lane >> 4) * 4;
#pragma unroll
  for (int m = 0; m < 2; m++) {
#pragma unroll
    for (int n = 0; n < 4; n++) {
      int col = col0 + n * 16 + lr;
      float bv = bias[col];
#pragma unroll
      for (int r = 0; r < 4; r++) {
        int row = row0 + wid * 32 + m * 16 + rb + r;
        out[(size_t)row * 1024 + col] = acc[m][n][r] + bv;
      }
    }
  }
}

// ---------------------------------------------------------------------------
// Flash attention (R13 structure, unchanged): swapped-operand, QBLK=128,
// single barrier per jt, static-max softmax, PV0 overlaps softmax1.
// ---------------------------------------------------------------------------
__global__ __launch_bounds__(256, 2) void attn_kernel(
    const bf16_t* __restrict__ qg, const bf16_t* __restrict__ kg,
    const bf16_t* __restrict__ vt, const bf16_t* __restrict__ relb,
    const float* __restrict__ mbias, bf16_t* __restrict__ ctx) {
  __shared__ bf16_t Kb[2][64 * 64];  // 16 KB
  __shared__ bf16_t Vb[2][64 * 64];  // 16 KB
  __shared__ bf16_t Rr[4][64 * 64];  // 32 KB ring (64-row chunks)
  __shared__ unsigned SC[4][688];    // 11 KB per-wave EL/PL scratch

  const int tid = threadIdx.x;
  const int lane = tid & 63;
  const int w = tid >> 6;

  const int id = blockIdx.x;
  const int id2 = (id & 7) * 64 + (id >> 3);
  const int it = id2 & 15;
  const int bh = id2 >> 4;
  const int h = bh & 15;
  const int b = bh >> 4;
  const int i0 = it * 128;

  const size_t base = ((size_t)bh) * 2048 * 64;
  const int lr = lane & 15;
  const int g = lane >> 4;
  const int lk = g * 8;
  const int srow = lane >> 3;
  const int t16 = lane & 7;
  const int swz = (lr & 7) << 3;

  const bf16_t* kgb = kg + base;
  const bf16_t* vgb = vt + base;
  const bf16_t* rgb = relb + (size_t)(1920 - i0) * 64;

  bf16x8 aq[2][2];
#pragma unroll
  for (int gq = 0; gq < 2; gq++) {
    const bf16_t* src =
        qg + base + (size_t)(i0 + w * 32 + gq * 16 + lr) * 64 + lk;
    aq[gq][0] = *(const bf16x8*)(src);
    aq[gq][1] = *(const bf16x8*)(src + 32);
  }

  float l0 = 0.f, l1 = 0.f;
  f32x4 o0[4], o1[4];
#pragma unroll
  for (int n = 0; n < 4; n++) {
    o0[n] = {0.f, 0.f, 0.f, 0.f};
    o1[n] = {0.f, 0.f, 0.f, 0.f};
  }

  const float* mb_base = mbias + (size_t)b * 2048;
  unsigned* scw = SC[w];
  int sh[4];
#pragma unroll
  for (int r = 0; r < 4; r++) sh[r] = ((r + lr + 1) & 1) << 4;

#pragma unroll
  for (int i = 0; i < 2; i++) {
    int chunk = i * 4 + w;
    int row = chunk * 8 + srow;
    GLDS16(kgb + row * 64 + ((t16 ^ (row & 7)) * 8),
           Kb[0] + chunk * 512 + lane * 8);
  }
#pragma unroll
  for (int i = 0; i < 2; i++) {
    int chunk = i * 4 + w;
    int p = chunk * 8 + srow;
    GLDS16(vgb + (size_t)p * 2048 + ((t16 ^ (p & 7)) * 8),
           Vb[0] + chunk * 512 + lane * 8);
  }
#pragma unroll
  for (int c = 0; c < 3; c++) {
#pragma unroll
    for (int i = 0; i < 2; i++) {
      int chunk = i * 4 + w;
      int row = chunk * 8 + srow;
      GLDS16(rgb + (size_t)(c * 64 + row) * 64 + ((t16 ^ (row & 7)) * 8),
             Rr[c] + chunk * 512 + lane * 8);
    }
  }
  __syncthreads();

  for (int jt = 0; jt < 32; jt++) {
    const int j0 = jt * 64;

    f32x4 mbv[4];
#pragma unroll
    for (int n = 0; n < 4; n++)
      mbv[n] = *(const f32x4*)&mb_base[j0 + n * 16 + g * 4];

    if (jt < 31) {
#pragma unroll
      for (int i = 0; i < 2; i++) {
        int chunk = i * 4 + w;
        int p = chunk * 8 + srow;
        GLDS16(vgb + (j0 + 64) + (size_t)p * 2048 + ((t16 ^ (p & 7)) * 8),
               Vb[(jt + 1) & 1] + chunk * 512 + lane * 8);
      }
      const bf16_t* kn = kgb + (size_t)(j0 + 64) * 64;
      bf16_t* kd = Kb[(jt + 1) & 1];
#pragma unroll
      for (int i = 0; i < 2; i++) {
        int chunk = i * 4 + w;
        int row = chunk * 8 + srow;
        GLDS16(kn + row * 64 + ((t16 ^ (row & 7)) * 8),
               kd + chunk * 512 + lane * 8);
      }
      const bf16_t* rs = rgb + (size_t)(jt + 3) * 64 * 64;
      bf16_t* rd = Rr[(jt + 3) & 3];
#pragma unroll
      for (int i = 0; i < 2; i++) {
        int chunk = i * 4 + w;
        int row = chunk * 8 + srow;
        GLDS16(rs + row * 64 + ((t16 ^ (row & 7)) * 8),
               rd + chunk * 512 + lane * 8);
      }
    }

    f32x4 sacc0[4], sacc1[4], er0[5], er1[5];
#pragma unroll
    for (int n = 0; n < 4; n++) {
      sacc0[n] = {0.f, 0.f, 0.f, 0.f};
      sacc1[n] = {0.f, 0.f, 0.f, 0.f};
    }
#pragma unroll
    for (int n = 0; n < 5; n++) {
      er0[n] = {0.f, 0.f, 0.f, 0.f};
      er1[n] = {0.f, 0.f, 0.f, 0.f};
    }
    const bf16_t* kcur = Kb[jt & 1];
    __builtin_amdgcn_s_setprio(1);
#pragma unroll
    for (int kk = 0; kk < 2; kk++) {
      int cbs = (kk * 32 + lk) ^ swz;
#pragma unroll
      for (int n = 0; n < 4; n++) {
        bf16x8 ak = *(const bf16x8*)&kcur[(n * 16 + lr) * 64 + cbs];
        sacc0[n] = mfma16(ak, aq[0][kk], sacc0[n]);
        sacc1[n] = mfma16(ak, aq[1][kk], sacc1[n]);
      }
#pragma unroll
      for (int fi = 0; fi < 6; fi++) {
        int f = 6 - 2 * w + fi;
        const bf16_t* rc = Rr[(jt + (f >> 2)) & 3];
        bf16x8 ar = *(const bf16x8*)&rc[((f & 3) * 16 + lr) * 64 + cbs];
        if (fi >= 1) er0[fi - 1] = mfma16(ar, aq[0][kk], er0[fi - 1]);
        if (fi <= 4) er1[fi] = mfma16(ar, aq[1][kk], er1[fi]);
      }
    }
    __builtin_amdgcn_s_setprio(0);

    const bf16_t* vcur = Vb[jt & 1];
    bf16x8 av[2][4];

    {
#pragma unroll
      for (int n2 = 0; n2 < 5; n2++) {
        uint2 u = {pack2(er0[n2][0], er0[n2][1]), pack2(er0[n2][2], er0[n2][3])};
        *(uint2*)&scw[lr * 42 + n2 * 8 + g * 2] = u;
      }
      float ps = 0.f;
      float e[4][4];
#pragma unroll
      for (int n = 0; n < 4; n++) {
#pragma unroll
        for (int r = 0; r < 4; r++) {
          int key = n * 16 + g * 4 + r;
          int idx = key - lr + 15;
          unsigned d = scw[lr * 42 + (idx >> 1)];
          float bias = __builtin_bit_cast(float, (d >> sh[r]) << 16);
          float s = sacc0[n][r] + bias + mbv[n][r];
          e[n][r] = exp2f(s - MCONST);
          ps += e[n][r];
        }
      }
      l0 += ps;
#pragma unroll
      for (int n = 0; n < 4; n++) {
        uint2 u = {pack2(e[n][0], e[n][1]), pack2(e[n][2], e[n][3])};
        *(uint2*)&scw[lr * 36 + n * 8 + g * 2] = u;
      }
      bf16x8 bp0[2];
      bp0[0] = __builtin_bit_cast(bf16x8, *(const uint4*)&scw[lr * 36 + g * 4]);
      bp0[1] =
          __builtin_bit_cast(bf16x8, *(const uint4*)&scw[lr * 36 + 16 + g * 4]);
#pragma unroll
      for (int kk = 0; kk < 2; kk++) {
        int cbs = (kk * 32 + lk) ^ swz;
#pragma unroll
        for (int n = 0; n < 4; n++)
          av[kk][n] = *(const bf16x8*)&vcur[(n * 16 + lr) * 64 + cbs];
      }
      __builtin_amdgcn_s_setprio(1);
#pragma unroll
      for (int kk = 0; kk < 2; kk++)
#pragma unroll
        for (int n = 0; n < 4; n++) o0[n] = mfma16(av[kk][n], bp0[kk], o0[n]);
      __builtin_amdgcn_s_setprio(0);
    }

    {
#pragma unroll
      for (int n2 = 0; n2 < 5; n2++) {
        uint2 u = {pack2(er1[n2][0], er1[n2][1]), pack2(er1[n2][2], er1[n2][3])};
        *(uint2*)&scw[lr * 42 + n2 * 8 + g * 2] = u;
      }
      float ps = 0.f;
      float e[4][4];
#pragma unroll
      for (int n = 0; n < 4; n++) {
#pragma unroll
        for (int r = 0; r < 4; r++) {
          int key = n * 16 + g * 4 + r;
          int idx = key - lr + 15;
          unsigned d = scw[lr * 42 + (idx >> 1)];
          float bias = __builtin_bit_cast(float, (d >> sh[r]) << 16);
          float s = sacc1[n][r] + bias + mbv[n][r];
          e[n][r] = exp2f(s - MCONST);
          ps += e[n][r];
        }
      }
      l1 += ps;
#pragma unroll
      for (int n = 0; n < 4; n++) {
        uint2 u = {pack2(e[n][0], e[n][1]), pack2(e[n][2], e[n][3])};
        *(uint2*)&scw[lr * 36 + n * 8 + g * 2] = u;
      }
      bf16x8 bp1[2];
      bp1[0] = __builtin_bit_cast(bf16x8, *(const uint4*)&scw[lr * 36 + g * 4]);
      bp1[1] =
          __builtin_bit_cast(bf16x8, *(const uint4*)&scw[lr * 36 + 16 + g * 4]);
      __builtin_amdgcn_s_setprio(1);
#pragma unroll
      for (int kk = 0; kk < 2; kk++)
#pragma unroll
        for (int n = 0; n < 4; n++) o1[n] = mfma16(av[kk][n], bp1[kk], o1[n]);
      __builtin_amdgcn_s_setprio(0);
    }

    __syncthreads();
  }

  l0 += __shfl_xor(l0, 16, 64);
  l0 += __shfl_xor(l0, 32, 64);
  l1 += __shfl_xor(l1, 16, 64);
  l1 += __shfl_xor(l1, 32, 64);

#pragma unroll
  for (int gq = 0; gq < 2; gq++) {
    f32x4* o = gq ? o1 : o0;
    float inv = 1.0f / (gq ? l1 : l0);
    size_t bt = (size_t)b * 2048 + i0 + w * 32 + gq * 16 + lr;
#pragma unroll
    for (int n = 0; n < 4; n++) {
      uint2 u = {pack2(o[n][0] * inv, o[n][1] * inv),
                 pack2(o[n][2] * inv, o[n][3] * inv)};
      *(uint2*)&ctx[bt * 1024 + h * 64 + n * 16 + g * 4] = u;
    }
  }
}

// ---------------------------------------------------------------------------
extern "C" void kernel_launch(void* const* d_in, const int* in_sizes, int n_in,
                              void* d_out, int out_size, void* d_ws,
                              size_t ws_size, hipStream_t stream) {
  (void)in_sizes; (void)n_in; (void)out_size; (void)ws_size;
  const float* Q    = (const float*)d_in[0];
  const float* K    = (const float*)d_in[1];
  const float* V    = (const float*)d_in[2];
  const float* mask = (const float*)d_in[3];
  const float* WQ   = (const float*)d_in[4];
  const float* WK   = (const float*)d_in[5];
  const float* WV   = (const float*)d_in[6];
  const float* rel  = (const float*)d_in[7];
  const float* dW   = (const float*)d_in[8];
  const float* db   = (const float*)d_in[9];
  float* out = (float*)d_out;

  const size_t N4M = (size_t)4096 * 1024;
  const size_t N1M = (size_t)1024 * 1024;
  bf16_t* wqt  = (bf16_t*)d_ws;
  bf16_t* wkt  = wqt + N1M;
  bf16_t* wvt  = wkt + N1M;
  bf16_t* dwt  = wvt + N1M;
  bf16_t* qb   = dwt + N1M;
  bf16_t* kb   = qb + N4M;
  bf16_t* vb   = kb + N4M;                     // V^T (b,h,p,t)
  bf16_t* ctxb = vb + N4M;
  bf16_t* relb = ctxb + N4M;                   // 4096*64 bf16
  float*  mbias = (float*)(relb + 4096 * 64);  // 4096 f32

  dim3 blk(256);
  transpose_w_kernel<<<dim3(256, 4), blk, 0, stream>>>(WQ, WK, WV, dW, wqt,
                                                       wkt, wvt, dwt);
  prep_kernel<<<dim3((4096 * 64 + 4096) / 256), blk, 0, stream>>>(rel, mask,
                                                                  relb, mbias);
  proj_gemm_kernel<<<dim3(32, 8, 3), blk, 0, stream>>>(Q, K, V, wqt, wkt, wvt,
                                                       qb, kb, vb);
  attn_kernel<<<dim3(512), blk, 0, stream>>>(qb, kb, vb, relb, mbias, ctxb);
  dense_gemm_kernel<<<dim3(32, 16), blk, 0, stream>>>(ctxb, dwt, db, out);
}

// Round 16
// 180.181 us; speedup vs baseline: 3.1725x; 1.0061x over previous
//
#include <hip/hip_runtime.h>
#include <hip/hip_bf16.h>

typedef __bf16 bf16_t;
typedef __bf16 bf16x2 __attribute__((ext_vector_type(2)));
typedef __bf16 bf16x8 __attribute__((ext_vector_type(8)));
typedef float f32x4 __attribute__((ext_vector_type(4)));

#define QSCALE 0.1803368801111396f   /* 0.125 * log2(e) */
#define MLOG2E 1.4426950408889634f
#define MCONST 12.0f                 /* static softmax max (log2 domain) */

__device__ __forceinline__ f32x4 mfma16(bf16x8 a, bf16x8 b, f32x4 c) {
  return __builtin_amdgcn_mfma_f32_16x16x32_bf16(a, b, c, 0, 0, 0);
}

#define GLDS16(gsrc, ldst)                                                     \
  __builtin_amdgcn_global_load_lds(                                            \
      (const __attribute__((address_space(1))) void*)(gsrc),                   \
      (__attribute__((address_space(3))) void*)(ldst), 16, 0, 0)

__device__ __forceinline__ unsigned pack2(float a, float b) {
  bf16x2 t = {(bf16_t)a, (bf16_t)b};
  return __builtin_bit_cast(unsigned, t);
}

// ---------------------------------------------------------------------------
// prep_all: y<4 -> transpose W mats to bf16 [col][k]; y==4 -> rel/mbias prep.
// ---------------------------------------------------------------------------
__global__ void prep_all_kernel(const float* __restrict__ WQ,
                                const float* __restrict__ WK,
                                const float* __restrict__ WV,
                                const float* __restrict__ dW,
                                const float* __restrict__ rel,
                                const float* __restrict__ mask,
                                bf16_t* __restrict__ wqt,
                                bf16_t* __restrict__ wkt,
                                bf16_t* __restrict__ wvt,
                                bf16_t* __restrict__ dwt,
                                bf16_t* __restrict__ relb,
                                float* __restrict__ mbias) {
  const int mat = blockIdx.y;
  if (mat == 4) {
    int idx = blockIdx.x * 256 + threadIdx.x;
    if (idx < 4096 * 64) {
      int row = idx >> 6;
      int col = idx & 63;
      int sr = row > 4094 ? 4094 : row;
      relb[idx] = (bf16_t)rel[sr * 64 + col];
    } else {
      int j = idx - 4096 * 64;
      if (j < 4096) mbias[j] = (1.0f - mask[j]) * -1e9f * MLOG2E;
    }
    return;
  }
  if (blockIdx.x >= 256) return;
  __shared__ float tl[64][65];
  const float* s = mat == 0 ? WQ : (mat == 1 ? WK : (mat == 2 ? WV : dW));
  bf16_t* d = mat == 0 ? wqt : (mat == 1 ? wkt : (mat == 2 ? wvt : dwt));
  const int tile = blockIdx.x;
  int row0, col0;
  size_t sstride;
  const float* sp;
  if (mat < 3) {
    int h = tile >> 4;
    row0 = (tile & 15) * 64;
    col0 = h * 64;
    sstride = 64;
    sp = s + (size_t)h * 65536 + (size_t)row0 * 64;
  } else {
    int nt = tile >> 4;
    row0 = (tile & 15) * 64;
    col0 = nt * 64;
    sstride = 1024;
    sp = s + (size_t)row0 * 1024 + (size_t)nt * 64;
  }
  const int t = threadIdx.x;
#pragma unroll
  for (int i = 0; i < 16; i++) {
    int lin = t + i * 256;
    int r = lin >> 6, c = lin & 63;
    tl[r][c] = sp[(size_t)r * sstride + c];
  }
  __syncthreads();
#pragma unroll
  for (int i = 0; i < 16; i++) {
    int lin = t + i * 256;
    int p = lin >> 6, k = lin & 63;
    d[(size_t)(col0 + p) * 1024 + row0 + k] = (bf16_t)tl[k][p];
  }
}

// ---------------------------------------------------------------------------
// Fused projection GEMM: A staged from f32 with fused pack2 (swizzled LDS
// write matches GLDS16-read layout); W staged via GLDS16 (bf16, transposed).
// z=0 -> qb scaled (b,h,t,p); z=1 -> kb; z=2 -> vb transposed (b,h,p,t).
// ---------------------------------------------------------------------------
__global__ __launch_bounds__(256) void proj_gemm_kernel(
    const float* __restrict__ Q, const float* __restrict__ K,
    const float* __restrict__ V, const bf16_t* __restrict__ WQt,
    const bf16_t* __restrict__ WKt, const bf16_t* __restrict__ WVt,
    bf16_t* __restrict__ qb, bf16_t* __restrict__ kb,
    bf16_t* __restrict__ vb) {
  const int z = blockIdx.z;
  const float* A = z == 0 ? Q : (z == 1 ? K : V);
  const bf16_t* Wt = z == 0 ? WQt : (z == 1 ? WKt : WVt);
  bf16_t* out = z == 0 ? qb : (z == 1 ? kb : vb);
  const float scale = z == 0 ? QSCALE : 1.0f;

  __shared__ bf16_t As[128 * 64];
  __shared__ bf16_t Bs[128 * 64];
  const int tid = threadIdx.x;
  const int lane = tid & 63;
  const int wid = tid >> 6;
  const int wm = wid >> 1, wn = wid & 1;
  const int row0 = blockIdx.x * 128;
  const int col0 = blockIdx.y * 128;
  const int lr = lane & 15;
  const int lk = (lane >> 4) * 8;
  const int srow = lane >> 3;
  const int t16 = lane & 7;
  const int swz = (lr & 7) << 3;

  f32x4 acc[4][4];
#pragma unroll
  for (int m = 0; m < 4; m++)
#pragma unroll
    for (int n = 0; n < 4; n++) acc[m][n] = {0.f, 0.f, 0.f, 0.f};

  for (int kt = 0; kt < 1024; kt += 64) {
#pragma unroll
    for (int i = 0; i < 4; i++) {
      int chunk = i * 4 + wid;
      int row = chunk * 8 + srow;
      int so = (t16 ^ (row & 7)) * 8;
      GLDS16(Wt + (size_t)(col0 + row) * 1024 + kt + so,
             Bs + chunk * 512 + lane * 8);
    }
#pragma unroll
    for (int i = 0; i < 4; i++) {
      int c = tid + i * 256;
      int row = c >> 3;
      int k8 = (c & 7) * 8;
      const float* src = A + (size_t)(row0 + row) * 1024 + kt + k8;
      float4 v0 = *(const float4*)(src);
      float4 v1 = *(const float4*)(src + 4);
      uint4 u = {pack2(v0.x, v0.y), pack2(v0.z, v0.w), pack2(v1.x, v1.y),
                 pack2(v1.z, v1.w)};
      *(uint4*)&As[row * 64 + (k8 ^ ((row & 7) << 3))] = u;
    }
    __syncthreads();
#pragma unroll
    for (int kk = 0; kk < 2; kk++) {
      int cbs = (kk * 32 + lk) ^ swz;
      bf16x8 af[4], bfr[4];
#pragma unroll
      for (int m = 0; m < 4; m++)
        af[m] = *(const bf16x8*)&As[(wm * 64 + m * 16 + lr) * 64 + cbs];
#pragma unroll
      for (int n = 0; n < 4; n++)
        bfr[n] = *(const bf16x8*)&Bs[(wn * 64 + n * 16 + lr) * 64 + cbs];
#pragma unroll
      for (int m = 0; m < 4; m++)
#pragma unroll
        for (int n = 0; n < 4; n++)
          acc[m][n] = mfma16(af[m], bfr[n], acc[m][n]);
    }
    __syncthreads();
  }
  const int rb = (lane >> 4) * 4;
#pragma unroll
  for (int m = 0; m < 4; m++) {
#pragma unroll
    for (int n = 0; n < 4; n++) {
      int col = col0 + wn * 64 + n * 16 + lr;
      int h = col >> 6, p = col & 63;
      int row_base = row0 + wm * 64 + m * 16 + rb;
      int b = row_base >> 11, t0 = row_base & 2047;
      if (z == 2) {
        uint2 u = {pack2(acc[m][n][0], acc[m][n][1]),
                   pack2(acc[m][n][2], acc[m][n][3])};
        *(uint2*)&out[(((size_t)(b * 16 + h) * 64 + p) * 2048) + t0] = u;
      } else {
#pragma unroll
        for (int r = 0; r < 4; r++) {
          out[(((size_t)(b * 16 + h) * 2048 + t0 + r) * 64) + p] =
              (bf16_t)(acc[m][n][r] * scale);
        }
      }
    }
  }
}

// ---------------------------------------------------------------------------
// Dense output GEMM, 128x64 tiles (grid 32x16 -> 2 blocks/CU):
// out = ctx(bf16) @ dwt^T + bias  (dwt is [n][k] bf16 row-major)
// ---------------------------------------------------------------------------
__global__ __launch_bounds__(256) void dense_gemm_kernel(
    const bf16_t* __restrict__ A, const bf16_t* __restrict__ Wt,
    const float* __restrict__ bias, float* __restrict__ out) {
  __shared__ bf16_t As[128 * 64];  // 16 KB
  __shared__ bf16_t Bs[64 * 64];   //  8 KB
  const int tid = threadIdx.x;
  const int lane = tid & 63;
  const int wid = tid >> 6;
  const int row0 = blockIdx.x * 128;
  const int col0 = blockIdx.y * 64;
  const int lr = lane & 15;
  const int lk = (lane >> 4) * 8;
  const int srow = lane >> 3;
  const int t16 = lane & 7;
  const int swz = (lr & 7) << 3;

  f32x4 acc[2][4];
#pragma unroll
  for (int m = 0; m < 2; m++)
#pragma unroll
    for (int n = 0; n < 4; n++) acc[m][n] = {0.f, 0.f, 0.f, 0.f};

  for (int kt = 0; kt < 1024; kt += 64) {
#pragma unroll
    for (int i = 0; i < 4; i++) {
      int chunk = i * 4 + wid;
      int row = chunk * 8 + srow;
      int so = (t16 ^ (row & 7)) * 8;
      GLDS16(A + (size_t)(row0 + row) * 1024 + kt + so,
             As + chunk * 512 + lane * 8);
    }
#pragma unroll
    for (int i = 0; i < 2; i++) {
      int chunk = i * 4 + wid;
      int row = chunk * 8 + srow;
      int so = (t16 ^ (row & 7)) * 8;
      GLDS16(Wt + (size_t)(col0 + row) * 1024 + kt + so,
             Bs + chunk * 512 + lane * 8);
    }
    __syncthreads();
#pragma unroll
    for (int kk = 0; kk < 2; kk++) {
      int cbs = (kk * 32 + lk) ^ swz;
      bf16x8 af[2], bfr[4];
#pragma unroll
      for (int m = 0; m < 2; m++)
        af[m] = *(const bf16x8*)&As[(wid * 32 + m * 16 + lr) * 64 + cbs];
#pragma unroll
      for (int n = 0; n < 4; n++)
        bfr[n] = *(const bf16x8*)&Bs[(n * 16 + lr) * 64 + cbs];
#pragma unroll
      for (int m = 0; m < 2; m++)
#pragma unroll
        for (int n = 0; n < 4; n++)
          acc[m][n] = mfma16(af[m], bfr[n], acc[m][n]);
    }
    __syncthreads();
  }
  const int rb = (lane >> 4) * 4;
#pragma unroll
  for (int m = 0; m < 2; m++) {
#pragma unroll
    for (int n = 0; n < 4; n++) {
      int col = col0 + n * 16 + lr;
      float bv = bias[col];
#pragma unroll
      for (int r = 0; r < 4; r++) {
        int row = row0 + wid * 32 + m * 16 + rb + r;
        out[(size_t)row * 1024 + col] = acc[m][n][r] + bv;
      }
    }
  }
}

// ---------------------------------------------------------------------------
// Flash attention (R13 structure): swapped-operand, QBLK=128, single barrier
// per jt, static-max softmax, PV0 overlaps softmax1.
// NEW: PL word-XOR swizzle w^=((lr>>2)&3)<<2 (breaks lr<->lr+8 bank alias,
// preserves b64/b128 alignment; applied on write and read identically).
// ---------------------------------------------------------------------------
__global__ __launch_bounds__(256, 2) void attn_kernel(
    const bf16_t* __restrict__ qg, const bf16_t* __restrict__ kg,
    const bf16_t* __restrict__ vt, const bf16_t* __restrict__ relb,
    const float* __restrict__ mbias, bf16_t* __restrict__ ctx) {
  __shared__ bf16_t Kb[2][64 * 64];  // 16 KB
  __shared__ bf16_t Vb[2][64 * 64];  // 16 KB
  __shared__ bf16_t Rr[4][64 * 64];  // 32 KB ring (64-row chunks)
  __shared__ unsigned SC[4][688];    // 11 KB per-wave EL/PL scratch

  const int tid = threadIdx.x;
  const int lane = tid & 63;
  const int w = tid >> 6;

  const int id = blockIdx.x;
  const int id2 = (id & 7) * 64 + (id >> 3);
  const int it = id2 & 15;
  const int bh = id2 >> 4;
  const int h = bh & 15;
  const int b = bh >> 4;
  const int i0 = it * 128;

  const size_t base = ((size_t)bh) * 2048 * 64;
  const int lr = lane & 15;
  const int g = lane >> 4;
  const int lk = g * 8;
  const int srow = lane >> 3;
  const int t16 = lane & 7;
  const int swz = (lr & 7) << 3;
  const int px = ((lr >> 2) & 3) << 2;  // PL word-XOR

  const bf16_t* kgb = kg + base;
  const bf16_t* vgb = vt + base;
  const bf16_t* rgb = relb + (size_t)(1920 - i0) * 64;

  bf16x8 aq[2][2];
#pragma unroll
  for (int gq = 0; gq < 2; gq++) {
    const bf16_t* src =
        qg + base + (size_t)(i0 + w * 32 + gq * 16 + lr) * 64 + lk;
    aq[gq][0] = *(const bf16x8*)(src);
    aq[gq][1] = *(const bf16x8*)(src + 32);
  }

  float l0 = 0.f, l1 = 0.f;
  f32x4 o0[4], o1[4];
#pragma unroll
  for (int n = 0; n < 4; n++) {
    o0[n] = {0.f, 0.f, 0.f, 0.f};
    o1[n] = {0.f, 0.f, 0.f, 0.f};
  }

  const float* mb_base = mbias + (size_t)b * 2048;
  unsigned* scw = SC[w];
  int sh[4];
#pragma unroll
  for (int r = 0; r < 4; r++) sh[r] = ((r + lr + 1) & 1) << 4;

#pragma unroll
  for (int i = 0; i < 2; i++) {
    int chunk = i * 4 + w;
    int row = chunk * 8 + srow;
    GLDS16(kgb + row * 64 + ((t16 ^ (row & 7)) * 8),
           Kb[0] + chunk * 512 + lane * 8);
  }
#pragma unroll
  for (int i = 0; i < 2; i++) {
    int chunk = i * 4 + w;
    int p = chunk * 8 + srow;
    GLDS16(vgb + (size_t)p * 2048 + ((t16 ^ (p & 7)) * 8),
           Vb[0] + chunk * 512 + lane * 8);
  }
#pragma unroll
  for (int c = 0; c < 3; c++) {
#pragma unroll
    for (int i = 0; i < 2; i++) {
      int chunk = i * 4 + w;
      int row = chunk * 8 + srow;
      GLDS16(rgb + (size_t)(c * 64 + row) * 64 + ((t16 ^ (row & 7)) * 8),
             Rr[c] + chunk * 512 + lane * 8);
    }
  }
  __syncthreads();

  for (int jt = 0; jt < 32; jt++) {
    const int j0 = jt * 64;

    f32x4 mbv[4];
#pragma unroll
    for (int n = 0; n < 4; n++)
      mbv[n] = *(const f32x4*)&mb_base[j0 + n * 16 + g * 4];

    if (jt < 31) {
#pragma unroll
      for (int i = 0; i < 2; i++) {
        int chunk = i * 4 + w;
        int p = chunk * 8 + srow;
        GLDS16(vgb + (j0 + 64) + (size_t)p * 2048 + ((t16 ^ (p & 7)) * 8),
               Vb[(jt + 1) & 1] + chunk * 512 + lane * 8);
      }
      const bf16_t* kn = kgb + (size_t)(j0 + 64) * 64;
      bf16_t* kd = Kb[(jt + 1) & 1];
#pragma unroll
      for (int i = 0; i < 2; i++) {
        int chunk = i * 4 + w;
        int row = chunk * 8 + srow;
        GLDS16(kn + row * 64 + ((t16 ^ (row & 7)) * 8),
               kd + chunk * 512 + lane * 8);
      }
      const bf16_t* rs = rgb + (size_t)(jt + 3) * 64 * 64;
      bf16_t* rd = Rr[(jt + 3) & 3];
#pragma unroll
      for (int i = 0; i < 2; i++) {
        int chunk = i * 4 + w;
        int row = chunk * 8 + srow;
        GLDS16(rs + row * 64 + ((t16 ^ (row & 7)) * 8),
               rd + chunk * 512 + lane * 8);
      }
    }

    f32x4 sacc0[4], sacc1[4], er0[5], er1[5];
#pragma unroll
    for (int n = 0; n < 4; n++) {
      sacc0[n] = {0.f, 0.f, 0.f, 0.f};
      sacc1[n] = {0.f, 0.f, 0.f, 0.f};
    }
#pragma unroll
    for (int n = 0; n < 5; n++) {
      er0[n] = {0.f, 0.f, 0.f, 0.f};
      er1[n] = {0.f, 0.f, 0.f, 0.f};
    }
    const bf16_t* kcur = Kb[jt & 1];
    __builtin_amdgcn_s_setprio(1);
#pragma unroll
    for (int kk = 0; kk < 2; kk++) {
      int cbs = (kk * 32 + lk) ^ swz;
#pragma unroll
      for (int n = 0; n < 4; n++) {
        bf16x8 ak = *(const bf16x8*)&kcur[(n * 16 + lr) * 64 + cbs];
        sacc0[n] = mfma16(ak, aq[0][kk], sacc0[n]);
        sacc1[n] = mfma16(ak, aq[1][kk], sacc1[n]);
      }
#pragma unroll
      for (int fi = 0; fi < 6; fi++) {
        int f = 6 - 2 * w + fi;
        const bf16_t* rc = Rr[(jt + (f >> 2)) & 3];
        bf16x8 ar = *(const bf16x8*)&rc[((f & 3) * 16 + lr) * 64 + cbs];
        if (fi >= 1) er0[fi - 1] = mfma16(ar, aq[0][kk], er0[fi - 1]);
        if (fi <= 4) er1[fi] = mfma16(ar, aq[1][kk], er1[fi]);
      }
    }
    __builtin_amdgcn_s_setprio(0);

    const bf16_t* vcur = Vb[jt & 1];
    bf16x8 av[2][4];

    {
#pragma unroll
      for (int n2 = 0; n2 < 5; n2++) {
        uint2 u = {pack2(er0[n2][0], er0[n2][1]), pack2(er0[n2][2], er0[n2][3])};
        *(uint2*)&scw[lr * 42 + n2 * 8 + g * 2] = u;
      }
      float ps = 0.f;
      float e[4][4];
#pragma unroll
      for (int n = 0; n < 4; n++) {
#pragma unroll
        for (int r = 0; r < 4; r++) {
          int key = n * 16 + g * 4 + r;
          int idx = key - lr + 15;
          unsigned d = scw[lr * 42 + (idx >> 1)];
          float bias = __builtin_bit_cast(float, (d >> sh[r]) << 16);
          float s = sacc0[n][r] + bias + mbv[n][r];
          e[n][r] = exp2f(s - MCONST);
          ps += e[n][r];
        }
      }
      l0 += ps;
#pragma unroll
      for (int n = 0; n < 4; n++) {
        uint2 u = {pack2(e[n][0], e[n][1]), pack2(e[n][2], e[n][3])};
        *(uint2*)&scw[lr * 36 + ((n * 8 + g * 2) ^ px)] = u;
      }
      bf16x8 bp0[2];
      bp0[0] = __builtin_bit_cast(bf16x8,
                                  *(const uint4*)&scw[lr * 36 + ((g * 4) ^ px)]);
      bp0[1] = __builtin_bit_cast(
          bf16x8, *(const uint4*)&scw[lr * 36 + ((16 + g * 4) ^ px)]);
#pragma unroll
      for (int kk = 0; kk < 2; kk++) {
        int cbs = (kk * 32 + lk) ^ swz;
#pragma unroll
        for (int n = 0; n < 4; n++)
          av[kk][n] = *(const bf16x8*)&vcur[(n * 16 + lr) * 64 + cbs];
      }
      __builtin_amdgcn_s_setprio(1);
#pragma unroll
      for (int kk = 0; kk < 2; kk++)
#pragma unroll
        for (int n = 0; n < 4; n++) o0[n] = mfma16(av[kk][n], bp0[kk], o0[n]);
      __builtin_amdgcn_s_setprio(0);
    }

    {
#pragma unroll
      for (int n2 = 0; n2 < 5; n2++) {
        uint2 u = {pack2(er1[n2][0], er1[n2][1]), pack2(er1[n2][2], er1[n2][3])};
        *(uint2*)&scw[lr * 42 + n2 * 8 + g * 2] = u;
      }
      float ps = 0.f;
      float e[4][4];
#pragma unroll
      for (int n = 0; n < 4; n++) {
#pragma unroll
        for (int r = 0; r < 4; r++) {
          int key = n * 16 + g * 4 + r;
          int idx = key - lr + 15;
          unsigned d = scw[lr * 42 + (idx >> 1)];
          float bias = __builtin_bit_cast(float, (d >> sh[r]) << 16);
          float s = sacc1[n][r] + bias + mbv[n][r];
          e[n][r] = exp2f(s - MCONST);
          ps += e[n][r];
        }
      }
      l1 += ps;
#pragma unroll
      for (int n = 0; n < 4; n++) {
        uint2 u = {pack2(e[n][0], e[n][1]), pack2(e[n][2], e[n][3])};
        *(uint2*)&scw[lr * 36 + ((n * 8 + g * 2) ^ px)] = u;
      }
      bf16x8 bp1[2];
      bp1[0] = __builtin_bit_cast(bf16x8,
                                  *(const uint4*)&scw[lr * 36 + ((g * 4) ^ px)]);
      bp1[1] = __builtin_bit_cast(
          bf16x8, *(const uint4*)&scw[lr * 36 + ((16 + g * 4) ^ px)]);
      __builtin_amdgcn_s_setprio(1);
#pragma unroll
      for (int kk = 0; kk < 2; kk++)
#pragma unroll
        for (int n = 0; n < 4; n++) o1[n] = mfma16(av[kk][n], bp1[kk], o1[n]);
      __builtin_amdgcn_s_setprio(0);
    }

    __syncthreads();
  }

  l0 += __shfl_xor(l0, 16, 64);
  l0 += __shfl_xor(l0, 32, 64);
  l1 += __shfl_xor(l1, 16, 64);
  l1 += __shfl_xor(l1, 32, 64);

#pragma unroll
  for (int gq = 0; gq < 2; gq++) {
    f32x4* o = gq ? o1 : o0;
    float inv = 1.0f / (gq ? l1 : l0);
    size_t bt = (size_t)b * 2048 + i0 + w * 32 + gq * 16 + lr;
#pragma unroll
    for (int n = 0; n < 4; n++) {
      uint2 u = {pack2(o[n][0] * inv, o[n][1] * inv),
                 pack2(o[n][2] * inv, o[n][3] * inv)};
      *(uint2*)&ctx[bt * 1024 + h * 64 + n * 16 + g * 4] = u;
    }
  }
}

// ---------------------------------------------------------------------------
extern "C" void kernel_launch(void* const* d_in, const int* in_sizes, int n_in,
                              void* d_out, int out_size, void* d_ws,
                              size_t ws_size, hipStream_t stream) {
  (void)in_sizes; (void)n_in; (void)out_size; (void)ws_size;
  const float* Q    = (const float*)d_in[0];
  const float* K    = (const float*)d_in[1];
  const float* V    = (const float*)d_in[2];
  const float* mask = (const float*)d_in[3];
  const float* WQ   = (const float*)d_in[4];
  const float* WK   = (const float*)d_in[5];
  const float* WV   = (const float*)d_in[6];
  const float* rel  = (const float*)d_in[7];
  const float* dW   = (const float*)d_in[8];
  const float* db   = (const float*)d_in[9];
  float* out = (float*)d_out;

  const size_t N4M = (size_t)4096 * 1024;
  const size_t N1M = (size_t)1024 * 1024;
  bf16_t* wqt  = (bf16_t*)d_ws;
  bf16_t* wkt  = wqt + N1M;
  bf16_t* wvt  = wkt + N1M;
  bf16_t* dwt  = wvt + N1M;
  bf16_t* qb   = dwt + N1M;
  bf16_t* kb   = qb + N4M;
  bf16_t* vb   = kb + N4M;                     // V^T (b,h,p,t)
  bf16_t* ctxb = vb + N4M;
  bf16_t* relb = ctxb + N4M;                   // 4096*64 bf16
  float*  mbias = (float*)(relb + 4096 * 64);  // 4096 f32

  dim3 blk(256);
  prep_all_kernel<<<dim3(1040, 5), blk, 0, stream>>>(WQ, WK, WV, dW, rel, mask,
                                                     wqt, wkt, wvt, dwt, relb,
                                                     mbias);
  proj_gemm_kernel<<<dim3(32, 8, 3), blk, 0, stream>>>(Q, K, V, wqt, wkt, wvt,
                                                       qb, kb, vb);
  attn_kernel<<<dim3(512), blk, 0, stream>>>(qb, kb, vb, relb, mbias, ctxb);
  dense_gemm_kernel<<<dim3(32, 16), blk, 0, stream>>>(ctxb, dwt, db, out);
}

// Round 17
// 178.485 us; speedup vs baseline: 3.2027x; 1.0095x over previous
//
#include <hip/hip_runtime.h>
#include <hip/hip_bf16.h>

typedef __bf16 bf16_t;
typedef __bf16 bf16x2 __attribute__((ext_vector_type(2)));
typedef __bf16 bf16x8 __attribute__((ext_vector_type(8)));
typedef float f32x4 __attribute__((ext_vector_type(4)));

#define QSCALE 0.1803368801111396f   /* 0.125 * log2(e) */
#define MLOG2E 1.4426950408889634f
#define MCONST 12.0f                 /* static softmax max (log2 domain) */

__device__ __forceinline__ f32x4 mfma16(bf16x8 a, bf16x8 b, f32x4 c) {
  return __builtin_amdgcn_mfma_f32_16x16x32_bf16(a, b, c, 0, 0, 0);
}

#define GLDS16(gsrc, ldst)                                                     \
  __builtin_amdgcn_global_load_lds(                                            \
      (const __attribute__((address_space(1))) void*)(gsrc),                   \
      (__attribute__((address_space(3))) void*)(ldst), 16, 0, 0)

__device__ __forceinline__ unsigned pack2(float a, float b) {
  bf16x2 t = {(bf16_t)a, (bf16_t)b};
  return __builtin_bit_cast(unsigned, t);
}

// ---------------------------------------------------------------------------
// prep_all: y<4 -> transpose W mats to bf16 [col][k]; y==4 -> rel/mbias prep.
// ---------------------------------------------------------------------------
__global__ void prep_all_kernel(const float* __restrict__ WQ,
                                const float* __restrict__ WK,
                                const float* __restrict__ WV,
                                const float* __restrict__ dW,
                                const float* __restrict__ rel,
                                const float* __restrict__ mask,
                                bf16_t* __restrict__ wqt,
                                bf16_t* __restrict__ wkt,
                                bf16_t* __restrict__ wvt,
                                bf16_t* __restrict__ dwt,
                                bf16_t* __restrict__ relb,
                                float* __restrict__ mbias) {
  const int mat = blockIdx.y;
  if (mat == 4) {
    int idx = blockIdx.x * 256 + threadIdx.x;
    if (idx < 4096 * 64) {
      int row = idx >> 6;
      int col = idx & 63;
      int sr = row > 4094 ? 4094 : row;
      relb[idx] = (bf16_t)rel[sr * 64 + col];
    } else {
      int j = idx - 4096 * 64;
      if (j < 4096) mbias[j] = (1.0f - mask[j]) * -1e9f * MLOG2E;
    }
    return;
  }
  if (blockIdx.x >= 256) return;
  __shared__ float tl[64][65];
  const float* s = mat == 0 ? WQ : (mat == 1 ? WK : (mat == 2 ? WV : dW));
  bf16_t* d = mat == 0 ? wqt : (mat == 1 ? wkt : (mat == 2 ? wvt : dwt));
  const int tile = blockIdx.x;
  int row0, col0;
  size_t sstride;
  const float* sp;
  if (mat < 3) {
    int h = tile >> 4;
    row0 = (tile & 15) * 64;
    col0 = h * 64;
    sstride = 64;
    sp = s + (size_t)h * 65536 + (size_t)row0 * 64;
  } else {
    int nt = tile >> 4;
    row0 = (tile & 15) * 64;
    col0 = nt * 64;
    sstride = 1024;
    sp = s + (size_t)row0 * 1024 + (size_t)nt * 64;
  }
  const int t = threadIdx.x;
#pragma unroll
  for (int i = 0; i < 16; i++) {
    int lin = t + i * 256;
    int r = lin >> 6, c = lin & 63;
    tl[r][c] = sp[(size_t)r * sstride + c];
  }
  __syncthreads();
#pragma unroll
  for (int i = 0; i < 16; i++) {
    int lin = t + i * 256;
    int p = lin >> 6, k = lin & 63;
    d[(size_t)(col0 + p) * 1024 + row0 + k] = (bf16_t)tl[k][p];
  }
}

// ---------------------------------------------------------------------------
// Fused projection GEMM: A staged from f32 with fused pack2 (swizzled LDS
// write matches GLDS16-read layout); W staged via GLDS16 (bf16, transposed).
// z=0 -> qb scaled (b,h,t,p); z=1 -> kb; z=2 -> vb transposed (b,h,p,t).
// ---------------------------------------------------------------------------
__global__ __launch_bounds__(256) void proj_gemm_kernel(
    const float* __restrict__ Q, const float* __restrict__ K,
    const float* __restrict__ V, const bf16_t* __restrict__ WQt,
    const bf16_t* __restrict__ WKt, const bf16_t* __restrict__ WVt,
    bf16_t* __restrict__ qb, bf16_t* __restrict__ kb,
    bf16_t* __restrict__ vb) {
  const int z = blockIdx.z;
  const float* A = z == 0 ? Q : (z == 1 ? K : V);
  const bf16_t* Wt = z == 0 ? WQt : (z == 1 ? WKt : WVt);
  bf16_t* out = z == 0 ? qb : (z == 1 ? kb : vb);
  const float scale = z == 0 ? QSCALE : 1.0f;

  __shared__ bf16_t As[128 * 64];
  __shared__ bf16_t Bs[128 * 64];
  const int tid = threadIdx.x;
  const int lane = tid & 63;
  const int wid = tid >> 6;
  const int wm = wid >> 1, wn = wid & 1;
  const int row0 = blockIdx.x * 128;
  const int col0 = blockIdx.y * 128;
  const int lr = lane & 15;
  const int lk = (lane >> 4) * 8;
  const int srow = lane >> 3;
  const int t16 = lane & 7;
  const int swz = (lr & 7) << 3;

  f32x4 acc[4][4];
#pragma unroll
  for (int m = 0; m < 4; m++)
#pragma unroll
    for (int n = 0; n < 4; n++) acc[m][n] = {0.f, 0.f, 0.f, 0.f};

  for (int kt = 0; kt < 1024; kt += 64) {
#pragma unroll
    for (int i = 0; i < 4; i++) {
      int chunk = i * 4 + wid;
      int row = chunk * 8 + srow;
      int so = (t16 ^ (row & 7)) * 8;
      GLDS16(Wt + (size_t)(col0 + row) * 1024 + kt + so,
             Bs + chunk * 512 + lane * 8);
    }
#pragma unroll
    for (int i = 0; i < 4; i++) {
      int c = tid + i * 256;
      int row = c >> 3;
      int k8 = (c & 7) * 8;
      const float* src = A + (size_t)(row0 + row) * 1024 + kt + k8;
      float4 v0 = *(const float4*)(src);
      float4 v1 = *(const float4*)(src + 4);
      uint4 u = {pack2(v0.x, v0.y), pack2(v0.z, v0.w), pack2(v1.x, v1.y),
                 pack2(v1.z, v1.w)};
      *(uint4*)&As[row * 64 + (k8 ^ ((row & 7) << 3))] = u;
    }
    __syncthreads();
#pragma unroll
    for (int kk = 0; kk < 2; kk++) {
      int cbs = (kk * 32 + lk) ^ swz;
      bf16x8 af[4], bfr[4];
#pragma unroll
      for (int m = 0; m < 4; m++)
        af[m] = *(const bf16x8*)&As[(wm * 64 + m * 16 + lr) * 64 + cbs];
#pragma unroll
      for (int n = 0; n < 4; n++)
        bfr[n] = *(const bf16x8*)&Bs[(wn * 64 + n * 16 + lr) * 64 + cbs];
#pragma unroll
      for (int m = 0; m < 4; m++)
#pragma unroll
        for (int n = 0; n < 4; n++)
          acc[m][n] = mfma16(af[m], bfr[n], acc[m][n]);
    }
    __syncthreads();
  }
  const int rb = (lane >> 4) * 4;
#pragma unroll
  for (int m = 0; m < 4; m++) {
#pragma unroll
    for (int n = 0; n < 4; n++) {
      int col = col0 + wn * 64 + n * 16 + lr;
      int h = col >> 6, p = col & 63;
      int row_base = row0 + wm * 64 + m * 16 + rb;
      int b = row_base >> 11, t0 = row_base & 2047;
      if (z == 2) {
        uint2 u = {pack2(acc[m][n][0], acc[m][n][1]),
                   pack2(acc[m][n][2], acc[m][n][3])};
        *(uint2*)&out[(((size_t)(b * 16 + h) * 64 + p) * 2048) + t0] = u;
      } else {
#pragma unroll
        for (int r = 0; r < 4; r++) {
          out[(((size_t)(b * 16 + h) * 2048 + t0 + r) * 64) + p] =
              (bf16_t)(acc[m][n][r] * scale);
        }
      }
    }
  }
}

// ---------------------------------------------------------------------------
// Dense output GEMM, 128x64 tiles (grid 32x16 -> 2 blocks/CU):
// out = ctx(bf16) @ dwt^T + bias  (dwt is [n][k] bf16 row-major)
// ---------------------------------------------------------------------------
__global__ __launch_bounds__(256) void dense_gemm_kernel(
    const bf16_t* __restrict__ A, const bf16_t* __restrict__ Wt,
    const float* __restrict__ bias, float* __restrict__ out) {
  __shared__ bf16_t As[128 * 64];  // 16 KB
  __shared__ bf16_t Bs[64 * 64];   //  8 KB
  const int tid = threadIdx.x;
  const int lane = tid & 63;
  const int wid = tid >> 6;
  const int row0 = blockIdx.x * 128;
  const int col0 = blockIdx.y * 64;
  const int lr = lane & 15;
  const int lk = (lane >> 4) * 8;
  const int srow = lane >> 3;
  const int t16 = lane & 7;
  const int swz = (lr & 7) << 3;

  f32x4 acc[2][4];
#pragma unroll
  for (int m = 0; m < 2; m++)
#pragma unroll
    for (int n = 0; n < 4; n++) acc[m][n] = {0.f, 0.f, 0.f, 0.f};

  for (int kt = 0; kt < 1024; kt += 64) {
#pragma unroll
    for (int i = 0; i < 4; i++) {
      int chunk = i * 4 + wid;
      int row = chunk * 8 + srow;
      int so = (t16 ^ (row & 7)) * 8;
      GLDS16(A + (size_t)(row0 + row) * 1024 + kt + so,
             As + chunk * 512 + lane * 8);
    }
#pragma unroll
    for (int i = 0; i < 2; i++) {
      int chunk = i * 4 + wid;
      int row = chunk * 8 + srow;
      int so = (t16 ^ (row & 7)) * 8;
      GLDS16(Wt + (size_t)(col0 + row) * 1024 + kt + so,
             Bs + chunk * 512 + lane * 8);
    }
    __syncthreads();
#pragma unroll
    for (int kk = 0; kk < 2; kk++) {
      int cbs = (kk * 32 + lk) ^ swz;
      bf16x8 af[2], bfr[4];
#pragma unroll
      for (int m = 0; m < 2; m++)
        af[m] = *(const bf16x8*)&As[(wid * 32 + m * 16 + lr) * 64 + cbs];
#pragma unroll
      for (int n = 0; n < 4; n++)
        bfr[n] = *(const bf16x8*)&Bs[(n * 16 + lr) * 64 + cbs];
#pragma unroll
      for (int m = 0; m < 2; m++)
#pragma unroll
        for (int n = 0; n < 4; n++)
          acc[m][n] = mfma16(af[m], bfr[n], acc[m][n]);
    }
    __syncthreads();
  }
  const int rb = (lane >> 4) * 4;
#pragma unroll
  for (int m = 0; m < 2; m++) {
#pragma unroll
    for (int n = 0; n < 4; n++) {
      int col = col0 + n * 16 + lr;
      float bv = bias[col];
#pragma unroll
      for (int r = 0; r < 4; r++) {
        int row = row0 + wid * 32 + m * 16 + rb + r;
        out[(size_t)row * 1024 + col] = acc[m][n][r] + bv;
      }
    }
  }
}

// ---------------------------------------------------------------------------
// Flash attention (R13/R15 structure — best measured): swapped-operand,
// QBLK=128, single barrier per jt, static-max softmax, PV0 overlaps softmax1.
// (R16's PL word-XOR swizzle REVERTED: it increased conflicts 7.3e6->9.4e6.)
// ---------------------------------------------------------------------------
__global__ __launch_bounds__(256, 2) void attn_kernel(
    const bf16_t* __restrict__ qg, const bf16_t* __restrict__ kg,
    const bf16_t* __restrict__ vt, const bf16_t* __restrict__ relb,
    const float* __restrict__ mbias, bf16_t* __restrict__ ctx) {
  __shared__ bf16_t Kb[2][64 * 64];  // 16 KB
  __shared__ bf16_t Vb[2][64 * 64];  // 16 KB
  __shared__ bf16_t Rr[4][64 * 64];  // 32 KB ring (64-row chunks)
  __shared__ unsigned SC[4][688];    // 11 KB per-wave EL/PL scratch

  const int tid = threadIdx.x;
  const int lane = tid & 63;
  const int w = tid >> 6;

  const int id = blockIdx.x;
  const int id2 = (id & 7) * 64 + (id >> 3);
  const int it = id2 & 15;
  const int bh = id2 >> 4;
  const int h = bh & 15;
  const int b = bh >> 4;
  const int i0 = it * 128;

  const size_t base = ((size_t)bh) * 2048 * 64;
  const int lr = lane & 15;
  const int g = lane >> 4;
  const int lk = g * 8;
  const int srow = lane >> 3;
  const int t16 = lane & 7;
  const int swz = (lr & 7) << 3;

  const bf16_t* kgb = kg + base;
  const bf16_t* vgb = vt + base;
  const bf16_t* rgb = relb + (size_t)(1920 - i0) * 64;

  bf16x8 aq[2][2];
#pragma unroll
  for (int gq = 0; gq < 2; gq++) {
    const bf16_t* src =
        qg + base + (size_t)(i0 + w * 32 + gq * 16 + lr) * 64 + lk;
    aq[gq][0] = *(const bf16x8*)(src);
    aq[gq][1] = *(const bf16x8*)(src + 32);
  }

  float l0 = 0.f, l1 = 0.f;
  f32x4 o0[4], o1[4];
#pragma unroll
  for (int n = 0; n < 4; n++) {
    o0[n] = {0.f, 0.f, 0.f, 0.f};
    o1[n] = {0.f, 0.f, 0.f, 0.f};
  }

  const float* mb_base = mbias + (size_t)b * 2048;
  unsigned* scw = SC[w];
  int sh[4];
#pragma unroll
  for (int r = 0; r < 4; r++) sh[r] = ((r + lr + 1) & 1) << 4;

#pragma unroll
  for (int i = 0; i < 2; i++) {
    int chunk = i * 4 + w;
    int row = chunk * 8 + srow;
    GLDS16(kgb + row * 64 + ((t16 ^ (row & 7)) * 8),
           Kb[0] + chunk * 512 + lane * 8);
  }
#pragma unroll
  for (int i = 0; i < 2; i++) {
    int chunk = i * 4 + w;
    int p = chunk * 8 + srow;
    GLDS16(vgb + (size_t)p * 2048 + ((t16 ^ (p & 7)) * 8),
           Vb[0] + chunk * 512 + lane * 8);
  }
#pragma unroll
  for (int c = 0; c < 3; c++) {
#pragma unroll
    for (int i = 0; i < 2; i++) {
      int chunk = i * 4 + w;
      int row = chunk * 8 + srow;
      GLDS16(rgb + (size_t)(c * 64 + row) * 64 + ((t16 ^ (row & 7)) * 8),
             Rr[c] + chunk * 512 + lane * 8);
    }
  }
  __syncthreads();

  for (int jt = 0; jt < 32; jt++) {
    const int j0 = jt * 64;

    f32x4 mbv[4];
#pragma unroll
    for (int n = 0; n < 4; n++)
      mbv[n] = *(const f32x4*)&mb_base[j0 + n * 16 + g * 4];

    if (jt < 31) {
#pragma unroll
      for (int i = 0; i < 2; i++) {
        int chunk = i * 4 + w;
        int p = chunk * 8 + srow;
        GLDS16(vgb + (j0 + 64) + (size_t)p * 2048 + ((t16 ^ (p & 7)) * 8),
               Vb[(jt + 1) & 1] + chunk * 512 + lane * 8);
      }
      const bf16_t* kn = kgb + (size_t)(j0 + 64) * 64;
      bf16_t* kd = Kb[(jt + 1) & 1];
#pragma unroll
      for (int i = 0; i < 2; i++) {
        int chunk = i * 4 + w;
        int row = chunk * 8 + srow;
        GLDS16(kn + row * 64 + ((t16 ^ (row & 7)) * 8),
               kd + chunk * 512 + lane * 8);
      }
      const bf16_t* rs = rgb + (size_t)(jt + 3) * 64 * 64;
      bf16_t* rd = Rr[(jt + 3) & 3];
#pragma unroll
      for (int i = 0; i < 2; i++) {
        int chunk = i * 4 + w;
        int row = chunk * 8 + srow;
        GLDS16(rs + row * 64 + ((t16 ^ (row & 7)) * 8),
               rd + chunk * 512 + lane * 8);
      }
    }

    f32x4 sacc0[4], sacc1[4], er0[5], er1[5];
#pragma unroll
    for (int n = 0; n < 4; n++) {
      sacc0[n] = {0.f, 0.f, 0.f, 0.f};
      sacc1[n] = {0.f, 0.f, 0.f, 0.f};
    }
#pragma unroll
    for (int n = 0; n < 5; n++) {
      er0[n] = {0.f, 0.f, 0.f, 0.f};
      er1[n] = {0.f, 0.f, 0.f, 0.f};
    }
    const bf16_t* kcur = Kb[jt & 1];
    __builtin_amdgcn_s_setprio(1);
#pragma unroll
    for (int kk = 0; kk < 2; kk++) {
      int cbs = (kk * 32 + lk) ^ swz;
#pragma unroll
      for (int n = 0; n < 4; n++) {
        bf16x8 ak = *(const bf16x8*)&kcur[(n * 16 + lr) * 64 + cbs];
        sacc0[n] = mfma16(ak, aq[0][kk], sacc0[n]);
        sacc1[n] = mfma16(ak, aq[1][kk], sacc1[n]);
      }
#pragma unroll
      for (int fi = 0; fi < 6; fi++) {
        int f = 6 - 2 * w + fi;
        const bf16_t* rc = Rr[(jt + (f >> 2)) & 3];
        bf16x8 ar = *(const bf16x8*)&rc[((f & 3) * 16 + lr) * 64 + cbs];
        if (fi >= 1) er0[fi - 1] = mfma16(ar, aq[0][kk], er0[fi - 1]);
        if (fi <= 4) er1[fi] = mfma16(ar, aq[1][kk], er1[fi]);
      }
    }
    __builtin_amdgcn_s_setprio(0);

    const bf16_t* vcur = Vb[jt & 1];
    bf16x8 av[2][4];

    {
#pragma unroll
      for (int n2 = 0; n2 < 5; n2++) {
        uint2 u = {pack2(er0[n2][0], er0[n2][1]), pack2(er0[n2][2], er0[n2][3])};
        *(uint2*)&scw[lr * 42 + n2 * 8 + g * 2] = u;
      }
      float ps = 0.f;
      float e[4][4];
#pragma unroll
      for (int n = 0; n < 4; n++) {
#pragma unroll
        for (int r = 0; r < 4; r++) {
          int key = n * 16 + g * 4 + r;
          int idx = key - lr + 15;
          unsigned d = scw[lr * 42 + (idx >> 1)];
          float bias = __builtin_bit_cast(float, (d >> sh[r]) << 16);
          float s = sacc0[n][r] + bias + mbv[n][r];
          e[n][r] = exp2f(s - MCONST);
          ps += e[n][r];
        }
      }
      l0 += ps;
#pragma unroll
      for (int n = 0; n < 4; n++) {
        uint2 u = {pack2(e[n][0], e[n][1]), pack2(e[n][2], e[n][3])};
        *(uint2*)&scw[lr * 36 + n * 8 + g * 2] = u;
      }
      bf16x8 bp0[2];
      bp0[0] = __builtin_bit_cast(bf16x8, *(const uint4*)&scw[lr * 36 + g * 4]);
      bp0[1] =
          __builtin_bit_cast(bf16x8, *(const uint4*)&scw[lr * 36 + 16 + g * 4]);
#pragma unroll
      for (int kk = 0; kk < 2; kk++) {
        int cbs = (kk * 32 + lk) ^ swz;
#pragma unroll
        for (int n = 0; n < 4; n++)
          av[kk][n] = *(const bf16x8*)&vcur[(n * 16 + lr) * 64 + cbs];
      }
      __builtin_amdgcn_s_setprio(1);
#pragma unroll
      for (int kk = 0; kk < 2; kk++)
#pragma unroll
        for (int n = 0; n < 4; n++) o0[n] = mfma16(av[kk][n], bp0[kk], o0[n]);
      __builtin_amdgcn_s_setprio(0);
    }

    {
#pragma unroll
      for (int n2 = 0; n2 < 5; n2++) {
        uint2 u = {pack2(er1[n2][0], er1[n2][1]), pack2(er1[n2][2], er1[n2][3])};
        *(uint2*)&scw[lr * 42 + n2 * 8 + g * 2] = u;
      }
      float ps = 0.f;
      float e[4][4];
#pragma unroll
      for (int n = 0; n < 4; n++) {
#pragma unroll
        for (int r = 0; r < 4; r++) {
          int key = n * 16 + g * 4 + r;
          int idx = key - lr + 15;
          unsigned d = scw[lr * 42 + (idx >> 1)];
          float bias = __builtin_bit_cast(float, (d >> sh[r]) << 16);
          float s = sacc1[n][r] + bias + mbv[n][r];
          e[n][r] = exp2f(s - MCONST);
          ps += e[n][r];
        }
      }
      l1 += ps;
#pragma unroll
      for (int n = 0; n < 4; n++) {
        uint2 u = {pack2(e[n][0], e[n][1]), pack2(e[n][2], e[n][3])};
        *(uint2*)&scw[lr * 36 + n * 8 + g * 2] = u;
      }
      bf16x8 bp1[2];
      bp1[0] = __builtin_bit_cast(bf16x8, *(const uint4*)&scw[lr * 36 + g * 4]);
      bp1[1] =
          __builtin_bit_cast(bf16x8, *(const uint4*)&scw[lr * 36 + 16 + g * 4]);
      __builtin_amdgcn_s_setprio(1);
#pragma unroll
      for (int kk = 0; kk < 2; kk++)
#pragma unroll
        for (int n = 0; n < 4; n++) o1[n] = mfma16(av[kk][n], bp1[kk], o1[n]);
      __builtin_amdgcn_s_setprio(0);
    }

    __syncthreads();
  }

  l0 += __shfl_xor(l0, 16, 64);
  l0 += __shfl_xor(l0, 32, 64);
  l1 += __shfl_xor(l1, 16, 64);
  l1 += __shfl_xor(l1, 32, 64);

#pragma unroll
  for (int gq = 0; gq < 2; gq++) {
    f32x4* o = gq ? o1 : o0;
    float inv = 1.0f / (gq ? l1 : l0);
    size_t bt = (size_t)b * 2048 + i0 + w * 32 + gq * 16 + lr;
#pragma unroll
    for (int n = 0; n < 4; n++) {
      uint2 u = {pack2(o[n][0] * inv, o[n][1] * inv),
                 pack2(o[n][2] * inv, o[n][3] * inv)};
      *(uint2*)&ctx[bt * 1024 + h * 64 + n * 16 + g * 4] = u;
    }
  }
}

// ---------------------------------------------------------------------------
extern "C" void kernel_launch(void* const* d_in, const int* in_sizes, int n_in,
                              void* d_out, int out_size, void* d_ws,
                              size_t ws_size, hipStream_t stream) {
  (void)in_sizes; (void)n_in; (void)out_size; (void)ws_size;
  const float* Q    = (const float*)d_in[0];
  const float* K    = (const float*)d_in[1];
  const float* V    = (const float*)d_in[2];
  const float* mask = (const float*)d_in[3];
  const float* WQ   = (const float*)d_in[4];
  const float* WK   = (const float*)d_in[5];
  const float* WV   = (const float*)d_in[6];
  const float* rel  = (const float*)d_in[7];
  const float* dW   = (const float*)d_in[8];
  const float* db   = (const float*)d_in[9];
  float* out = (float*)d_out;

  const size_t N4M = (size_t)4096 * 1024;
  const size_t N1M = (size_t)1024 * 1024;
  bf16_t* wqt  = (bf16_t*)d_ws;
  bf16_t* wkt  = wqt + N1M;
  bf16_t* wvt  = wkt + N1M;
  bf16_t* dwt  = wvt + N1M;
  bf16_t* qb   = dwt + N1M;
  bf16_t* kb   = qb + N4M;
  bf16_t* vb   = kb + N4M;                     // V^T (b,h,p,t)
  bf16_t* ctxb = vb + N4M;
  bf16_t* relb = ctxb + N4M;                   // 4096*64 bf16
  float*  mbias = (float*)(relb + 4096 * 64);  // 4096 f32

  dim3 blk(256);
  prep_all_kernel<<<dim3(1040, 5), blk, 0, stream>>>(WQ, WK, WV, dW, rel, mask,
                                                     wqt, wkt, wvt, dwt, relb,
                                                     mbias);
  proj_gemm_kernel<<<dim3(32, 8, 3), blk, 0, stream>>>(Q, K, V, wqt, wkt, wvt,
                                                       qb, kb, vb);
  attn_kernel<<<dim3(512), blk, 0, stream>>>(qb, kb, vb, relb, mbias, ctxb);
  dense_gemm_kernel<<<dim3(32, 16), blk, 0, stream>>>(ctxb, dwt, db, out);
}